// Round 8
// baseline (472.517 us; speedup 1.0000x reference)
//
#include <hip/hip_runtime.h>

#define NE 524288
#define NN 32768
#define NB 1024

#define F4(p) (*(const float4*)(p))

typedef __bf16 bf16x8 __attribute__((ext_vector_type(8)));
typedef float  f32x4  __attribute__((ext_vector_type(4)));

__device__ __forceinline__ float sigmoidf_(float v) { return 1.f / (1.f + expf(-v)); }

__device__ __forceinline__ void bf16split(float f, short &hi, short &lo) {
  unsigned u = __float_as_uint(f);
  unsigned rh = (u + 0x7FFFu + ((u >> 16) & 1u)) >> 16;
  float fh = __uint_as_float(rh << 16);
  float fl = f - fh;
  unsigned u2 = __float_as_uint(fl);
  unsigned rl = (u2 + 0x7FFFu + ((u2 >> 16) & 1u)) >> 16;
  hi = (short)rh; lo = (short)rl;
}

__device__ __forceinline__ unsigned short f2bf(float f) {
  unsigned u = __float_as_uint(f);
  return (unsigned short)((u + 0x7FFFu + ((u >> 16) & 1u)) >> 16);
}
__device__ __forceinline__ float bf2f(unsigned short h) {
  return __uint_as_float(((unsigned)h) << 16);
}

__device__ __forceinline__ void ld32(float* xr, const float* p) {
#pragma unroll
  for (int i = 0; i < 32; i += 4) {
    float4 v = F4(&p[i]);
    xr[i] = v.x; xr[i+1] = v.y; xr[i+2] = v.z; xr[i+3] = v.w;
  }
}

__device__ __forceinline__ float dot32r(const float* __restrict__ w, const float* xr) {
  float s = 0.f;
#pragma unroll
  for (int i = 0; i < 32; i += 4) {
    float4 ww = F4(&w[i]);
    s = fmaf(xr[i],   ww.x, s);
    s = fmaf(xr[i+1], ww.y, s);
    s = fmaf(xr[i+2], ww.z, s);
    s = fmaf(xr[i+3], ww.w, s);
  }
  return s;
}

// ---------------- embedding ----------------
__global__ __launch_bounds__(128) void embed_kernel(
    const float* __restrict__ xa, const float* __restrict__ W,
    const float* __restrict__ b, float* __restrict__ x)
{
  __shared__ float a[64];
  const int n = blockIdx.x, t = threadIdx.x;
  if (t < 64) a[t] = xa[n*64 + t];
  __syncthreads();
  float s = b[t];
#pragma unroll 8
  for (int f = 0; f < 64; ++f) s = fmaf(a[f], W[f*128 + t], s);
  x[n*128 + t] = s;
}

// ---------------- CSR build ----------------
__global__ __launch_bounds__(256) void hist_kernel(const int* __restrict__ ei, int* __restrict__ cnt) {
  const int e = blockIdx.x*256 + threadIdx.x;
  atomicAdd(&cnt[ei[NE + e]], 1);
}

__global__ __launch_bounds__(1024) void scan_kernel(
    const int* __restrict__ cnt, int* __restrict__ off, int* __restrict__ cur)
{
  __shared__ int wsum[16];
  const int t = threadIdx.x;
  int local[32];
  const int base = t*32;
  int s = 0;
#pragma unroll
  for (int i = 0; i < 32; ++i) { local[i] = cnt[base+i]; s += local[i]; }
  int pre = s;
  const int lane = t & 63;
#pragma unroll
  for (int o = 1; o < 64; o <<= 1) { int v = __shfl_up(pre, o); if (lane >= o) pre += v; }
  if (lane == 63) wsum[t >> 6] = pre;
  __syncthreads();
  if (t == 0) { int a = 0; for (int w = 0; w < 16; ++w) { int v = wsum[w]; wsum[w] = a; a += v; } }
  __syncthreads();
  int excl = wsum[t >> 6] + pre - s;
#pragma unroll
  for (int i = 0; i < 32; ++i) { off[base+i] = excl; cur[base+i] = excl; excl += local[i]; }
  if (t == 1023) off[NN] = excl;
}

// edge record: {src_as_float, d, 1/(1+d), exp(-d)} -> one float4 broadcast load in agg
__global__ __launch_bounds__(256) void scatter_kernel(
    const float* __restrict__ pos, const int* __restrict__ ei,
    int* __restrict__ cur, float4* __restrict__ csr_rec)
{
  const int e = blockIdx.x*256 + threadIdx.x;
  const int s = ei[e];
  const int d = ei[NE + e];
  float dx = pos[d*3+0] - pos[s*3+0];
  float dy = pos[d*3+1] - pos[s*3+1];
  float dz = pos[d*3+2] - pos[s*3+2];
  float dist = sqrtf(dx*dx + dy*dy + dz*dz + 1e-12f);
  const int slot = atomicAdd(&cur[d], 1);
  csr_rec[slot] = make_float4(__int_as_float(s), dist, 1.f/(1.f + dist), expf(-dist));
}

// ---------------- weight prep: split-bf16, MFMA-frag-major ----------------
__device__ __forceinline__ void pack_decode(int r, int N, int &k, int &n) {
  const int j = r & 7, lane = (r >> 3) & 63, rest = r >> 9;
  const int NT = N >> 4;
  const int t = rest % NT, kc = rest / NT;
  k = kc*32 + (lane >> 4)*8 + j;
  n = t*16 + (lane & 15);
}

// segment offsets (elements)
#define W1AB_OFF 0        // l*32768, K=128 N=256
#define W2_OFF   98304    // l*16384, K=128 N=128
#define WIN_OFF  147456   // K=128 N=384
#define WOUT_OFF 196608   // K=128 N=128
#define HA_OFF   212992   // K=224 N=256  meW1 gated
#define HB_OFF   270336   // K=256 N=256  blockdiag meW2
#define HL_OFF   335872   // K=64  N=256  leW1 gated
#define HD_OFF   352256   // K=256 N=256  blockdiag leW2
#define HF1_OFF  417792   // K=1024 N=512 blockdiag fW1
#define HF2_OFF  942080   // K=512 N=256  blockdiag fW2
#define HH1_OFF  1073152  // K=256 N=128  blockdiag hW1
#define PK_TOTAL 1105920

__global__ __launch_bounds__(256) void prep_kernel(
    const float* __restrict__ mp_W1, const float* __restrict__ mp_W2,
    const float* __restrict__ win, const float* __restrict__ wout,
    const float* __restrict__ mp_b1,
    const float* __restrict__ mol_gate, const float* __restrict__ lrn_gate,
    const float* __restrict__ meW1, const float* __restrict__ meW2,
    const float* __restrict__ leW1, const float* __restrict__ leW2,
    const float* __restrict__ fW1, const float* __restrict__ fW2,
    const float* __restrict__ hW1,
    short* __restrict__ bh, short* __restrict__ bl, float* __restrict__ pqbias)
{
  const int i = blockIdx.x*256 + threadIdx.x;
  if (i < 768) { const int l = i >> 8, t = i & 255; pqbias[i] = t < 128 ? mp_b1[l*128 + t] : 0.f; }
  if (i >= PK_TOTAL) return;
  int k, n; float v;
  if (i < W2_OFF) {
    const int l = i / 32768, r = i % 32768;
    pack_decode(r, 256, k, n);
    const float* W = mp_W1 + (size_t)l*259*128;
    v = (n < 128) ? W[k*128 + n] : W[(128+k)*128 + (n-128)];
  } else if (i < WIN_OFF) {
    const int q = i - W2_OFF, l = q / 16384, r = q % 16384;
    pack_decode(r, 128, k, n);
    v = mp_W2[(size_t)l*16384 + k*128 + n];
  } else if (i < WOUT_OFF) {
    pack_decode(i - WIN_OFF, 384, k, n);
    v = win[n*128 + k];
  } else if (i < HA_OFF) {
    pack_decode(i - WOUT_OFF, 128, k, n);
    v = wout[n*128 + k];
  } else if (i < HB_OFF) {           // meW1 gated: K=224 N=256
    pack_decode(i - HA_OFF, 256, k, n);
    const int p = n >> 6, h = n & 63;
    v = (k < 200) ? meW1[p*12800 + k*64 + h] * sigmoidf_(mol_gate[p*200 + k]) : 0.f;
  } else if (i < HL_OFF) {           // blockdiag meW2: K=256 N=256
    pack_decode(i - HB_OFF, 256, k, n);
    const int p = n >> 6, h = n & 63, kp = k >> 6, c = k & 63;
    v = (kp == p) ? meW2[p*4096 + c*64 + h] : 0.f;
  } else if (i < HD_OFF) {           // leW1 gated: K=64 N=256
    pack_decode(i - HL_OFF, 256, k, n);
    const int p = n >> 6, h = n & 63;
    v = leW1[p*4096 + k*64 + h] * sigmoidf_(lrn_gate[p*64 + k]);
  } else if (i < HF1_OFF) {          // blockdiag leW2: K=256 N=256
    pack_decode(i - HD_OFF, 256, k, n);
    const int p = n >> 6, h = n & 63, kp = k >> 6, c = k & 63;
    v = (kp == p) ? leW2[p*4096 + c*64 + h] : 0.f;
  } else if (i < HF2_OFF) {          // blockdiag fW1: K=1024 N=512
    pack_decode(i - HF1_OFF, 512, k, n);
    const int p = n >> 7, h = n & 127, kp = k >> 8, c = k & 255;
    v = (kp == p) ? fW1[p*32768 + c*128 + h] : 0.f;
  } else if (i < HH1_OFF) {          // blockdiag fW2: K=512 N=256
    pack_decode(i - HF2_OFF, 256, k, n);
    const int p = n >> 6, h = n & 63, kp = k >> 7, c = k & 127;
    v = (kp == p) ? fW2[p*8192 + c*64 + h] : 0.f;
  } else {                           // blockdiag hW1: K=256 N=128
    pack_decode(i - HH1_OFF, 128, k, n);
    const int p = n >> 5, h = n & 31, kp = k >> 6, c = k & 63;
    v = (kp == p) ? hW1[p*2048 + c*32 + h] : 0.f;
  }
  short h_, lo; bf16split(v, h_, lo);
  bh[i] = h_; bl[i] = lo;
}

// ---------------- generic MFMA GEMM: C[M][·] = op(A[M][K] @ B + bias) ----------------
// block = 4 waves; wave = 32 rows x 64 cols; grid = (M/128, ncols/64). split-bf16 3-term.
// dstcol = (col>>6)*colstride + coloff + (col&63)  (identity: colstride=64, coloff=0)
// If qbf != null, cols >= 128 go to qbf as bf16 (pq path).
__global__ __launch_bounds__(256, 2) void mfma_gemm_kernel(
    const float* __restrict__ A, int lda, int K,
    const short* __restrict__ Bh, const short* __restrict__ Bl,
    const float* __restrict__ bias, float* __restrict__ C, int ncols, int ldc,
    int colstride, int coloff, int relu,
    unsigned short* __restrict__ qbf)
{
  const int lane = threadIdx.x & 63, wid = threadIdx.x >> 6;
  const int m0 = blockIdx.x * 128 + wid * 32;
  const int n0 = blockIdx.y * 64;
  const int NT = ncols >> 4;
  const int cl = lane & 15, kg = lane >> 4;
  const int KC = K >> 5;

  f32x4 acc[2][4];
#pragma unroll
  for (int s = 0; s < 2; ++s)
#pragma unroll
    for (int t = 0; t < 4; ++t) acc[s][t] = (f32x4){0.f,0.f,0.f,0.f};

  for (int kc = 0; kc < KC; ++kc) {
    bf16x8 Ah[2], Al[2];
#pragma unroll
    for (int s = 0; s < 2; ++s) {
      const float* ap = &A[(size_t)(m0 + s*16 + cl)*lda + kc*32 + kg*8];
      const float4 f0 = F4(ap), f1 = F4(ap + 4);
      const float fv[8] = {f0.x,f0.y,f0.z,f0.w,f1.x,f1.y,f1.z,f1.w};
      union { short s[8]; bf16x8 b; } uh, ul;
#pragma unroll
      for (int j = 0; j < 8; ++j) bf16split(fv[j], uh.s[j], ul.s[j]);
      Ah[s] = uh.b; Al[s] = ul.b;
    }
    bf16x8 Bfh[4], Bfl[4];
#pragma unroll
    for (int t = 0; t < 4; ++t) {
      const size_t off = (((size_t)(kc*NT + (n0 >> 4) + t))*64 + lane)*8;
      Bfh[t] = *(const bf16x8*)&Bh[off];
      Bfl[t] = *(const bf16x8*)&Bl[off];
    }
#pragma unroll
    for (int s = 0; s < 2; ++s)
#pragma unroll
      for (int t = 0; t < 4; ++t)
        acc[s][t] = __builtin_amdgcn_mfma_f32_16x16x32_bf16(Ah[s], Bfh[t], acc[s][t], 0, 0, 0);
#pragma unroll
    for (int s = 0; s < 2; ++s)
#pragma unroll
      for (int t = 0; t < 4; ++t)
        acc[s][t] = __builtin_amdgcn_mfma_f32_16x16x32_bf16(Ah[s], Bfl[t], acc[s][t], 0, 0, 0);
#pragma unroll
    for (int s = 0; s < 2; ++s)
#pragma unroll
      for (int t = 0; t < 4; ++t)
        acc[s][t] = __builtin_amdgcn_mfma_f32_16x16x32_bf16(Al[s], Bfh[t], acc[s][t], 0, 0, 0);
  }

#pragma unroll
  for (int t = 0; t < 4; ++t) {
    const int col = n0 + t*16 + cl;
    const float bv = bias[col];
    const int dstcol = (col >> 6)*colstride + coloff + (col & 63);
#pragma unroll
    for (int s = 0; s < 2; ++s) {
      const int rbase = m0 + s*16 + kg*4;
#pragma unroll
      for (int r = 0; r < 4; ++r) {
        float v = acc[s][t][r] + bv;
        if (relu) v = fmaxf(v, 0.f);
        if (qbf && col >= 128)
          qbf[(size_t)(rbase + r)*128 + (col - 128)] = f2bf(v);
        else
          C[(size_t)(rbase + r)*ldc + dstcol] = v;
      }
    }
  }
}

// ---------------- MFMA GEMM + residual + LN ----------------
__global__ __launch_bounds__(256, 2) void mfma_gemm_ln_kernel(
    const float* __restrict__ A, int lda,
    const short* __restrict__ Bh, const short* __restrict__ Bl,
    const float* __restrict__ b2, const int* __restrict__ csr_off,
    const float* __restrict__ g, const float* __restrict__ bb,
    float* __restrict__ x)
{
  const int lane = threadIdx.x & 63, wid = threadIdx.x >> 6;
  const int m0 = blockIdx.x * 64 + wid * 16;
  const int cl = lane & 15, kg = lane >> 4;

  bf16x8 Ah[4], Al[4];
#pragma unroll
  for (int kc = 0; kc < 4; ++kc) {
    const float* ap = &A[(size_t)(m0 + cl)*lda + kc*32 + kg*8];
    const float4 f0 = F4(ap), f1 = F4(ap + 4);
    const float fv[8] = {f0.x,f0.y,f0.z,f0.w,f1.x,f1.y,f1.z,f1.w};
    union { short s[8]; bf16x8 b; } uh, ul;
#pragma unroll
    for (int j = 0; j < 8; ++j) bf16split(fv[j], uh.s[j], ul.s[j]);
    Ah[kc] = uh.b; Al[kc] = ul.b;
  }

  f32x4 acc[8];
#pragma unroll
  for (int t = 0; t < 8; ++t) acc[t] = (f32x4){0.f,0.f,0.f,0.f};

#pragma unroll
  for (int kc = 0; kc < 4; ++kc) {
    bf16x8 Bfh[8], Bfl[8];
#pragma unroll
    for (int t = 0; t < 8; ++t) {
      const size_t off = (((size_t)(kc*8 + t))*64 + lane)*8;
      Bfh[t] = *(const bf16x8*)&Bh[off];
      Bfl[t] = *(const bf16x8*)&Bl[off];
    }
#pragma unroll
    for (int t = 0; t < 8; ++t)
      acc[t] = __builtin_amdgcn_mfma_f32_16x16x32_bf16(Ah[kc], Bfh[t], acc[t], 0, 0, 0);
#pragma unroll
    for (int t = 0; t < 8; ++t)
      acc[t] = __builtin_amdgcn_mfma_f32_16x16x32_bf16(Ah[kc], Bfl[t], acc[t], 0, 0, 0);
#pragma unroll
    for (int t = 0; t < 8; ++t)
      acc[t] = __builtin_amdgcn_mfma_f32_16x16x32_bf16(Al[kc], Bfh[t], acc[t], 0, 0, 0);
  }

  const int r0 = m0 + kg*4;
  float sflag[4];
#pragma unroll
  for (int r = 0; r < 4; ++r)
    sflag[r] = (csr_off[r0 + r + 1] > csr_off[r0 + r]) ? 1.f : 0.f;

  float ps[4] = {0.f,0.f,0.f,0.f}, pq[4] = {0.f,0.f,0.f,0.f};
  float yv[8][4];
#pragma unroll
  for (int t = 0; t < 8; ++t) {
    const int col = t*16 + cl;
    const float b2v = b2[col];
#pragma unroll
    for (int r = 0; r < 4; ++r) {
      const float y = acc[t][r] + sflag[r]*b2v + x[(size_t)(r0 + r)*128 + col];
      yv[t][r] = y;
      ps[r] += y;
      pq[r] = fmaf(y, y, pq[r]);
    }
  }
#pragma unroll
  for (int o = 1; o < 16; o <<= 1) {
#pragma unroll
    for (int r = 0; r < 4; ++r) { ps[r] += __shfl_xor(ps[r], o); pq[r] += __shfl_xor(pq[r], o); }
  }
#pragma unroll
  for (int r = 0; r < 4; ++r) {
    const float mu = ps[r] * (1.f/128.f);
    const float var = pq[r]*(1.f/128.f) - mu*mu;
    const float rstd = rsqrtf(var + 1e-5f);
#pragma unroll
    for (int t = 0; t < 8; ++t) {
      const int col = t*16 + cl;
      x[(size_t)(r0 + r)*128 + col] = (yv[t][r] - mu)*rstd*g[col] + bb[col];
    }
  }
}

// ---------------- aggregation: P[n] <- mean_e relu(P[n]+Qbf[src]+df@W1c) ----------------
__global__ __launch_bounds__(256, 6) void agg_kernel(
    float* __restrict__ P, const unsigned short* __restrict__ Qbf,
    const int* __restrict__ csr_off, const float4* __restrict__ csr_rec,
    const float* __restrict__ W1)
{
  const int tid = threadIdx.x;
  const int node = blockIdx.x*4 + (tid >> 6);
  const int lane = tid & 63;
  const int c0 = lane*2;
  const int off0 = csr_off[node], off1 = csr_off[node+1];

  const float* __restrict__ w1c = W1 + 256*128;
  const float w00 = w1c[c0],       w01 = w1c[c0+1];
  const float w10 = w1c[128+c0],   w11 = w1c[128+c0+1];
  const float w20 = w1c[256+c0],   w21 = w1c[256+c0+1];
  const float2 p = *(const float2*)&P[(size_t)node*128 + c0];

  float a0 = 0.f, a1 = 0.f;
  int e = off0;
  for (; e + 8 <= off1; e += 8) {
    float4 rc[8];
#pragma unroll
    for (int j = 0; j < 8; ++j) rc[j] = csr_rec[e+j];
    ushort2 qv[8];
#pragma unroll
    for (int j = 0; j < 8; ++j)
      qv[j] = *(const ushort2*)&Qbf[(size_t)__float_as_int(rc[j].x)*128 + c0];
#pragma unroll
    for (int j = 0; j < 8; ++j) {
      float h0 = p.x + bf2f(qv[j].x);
      h0 = fmaf(rc[j].y, w00, h0); h0 = fmaf(rc[j].z, w10, h0); h0 = fmaf(rc[j].w, w20, h0);
      float h1 = p.y + bf2f(qv[j].y);
      h1 = fmaf(rc[j].y, w01, h1); h1 = fmaf(rc[j].z, w11, h1); h1 = fmaf(rc[j].w, w21, h1);
      a0 += fmaxf(h0, 0.f);
      a1 += fmaxf(h1, 0.f);
    }
  }
  for (; e < off1; ++e) {
    const float4 rc = csr_rec[e];
    const ushort2 qv = *(const ushort2*)&Qbf[(size_t)__float_as_int(rc.x)*128 + c0];
    float h0 = p.x + bf2f(qv.x);
    h0 = fmaf(rc.y, w00, h0); h0 = fmaf(rc.z, w10, h0); h0 = fmaf(rc.w, w20, h0);
    float h1 = p.y + bf2f(qv.y);
    h1 = fmaf(rc.y, w01, h1); h1 = fmaf(rc.z, w11, h1); h1 = fmaf(rc.w, w21, h1);
    a0 += fmaxf(h0, 0.f);
    a1 += fmaxf(h1, 0.f);
  }
  const int deg = off1 - off0;
  const float rc_ = deg > 0 ? 1.f/(float)deg : 1.f;
  *(float2*)&P[(size_t)node*128 + c0] = make_float2(a0*rc_, a1*rc_);
}

// ---------------- per-molecule attention on dqkv[n][384]; O -> dv slot ----------------
__global__ __launch_bounds__(128) void attn_kernel(float* __restrict__ dqkv)
{
  __shared__ float sk[32*132];
  __shared__ float sv[32*132];
  const int tid = threadIdx.x;
  const int b = blockIdx.x;

  for (int idx = tid; idx < 1024; idx += 128) {
    const int a = idx >> 5, c4 = idx & 31;
    *(float4*)&sk[a*132 + c4*4] = F4(&dqkv[(size_t)(b*32+a)*384 + 128 + c4*4]);
    *(float4*)&sv[a*132 + c4*4] = F4(&dqkv[(size_t)(b*32+a)*384 + 256 + c4*4]);
  }
  __syncthreads();

  const int h = tid >> 5, qr = tid & 31;
  float qreg[32];
  ld32(qreg, &dqkv[(size_t)(b*32+qr)*384 + h*32]);

  float sc[32];
#pragma unroll
  for (int k = 0; k < 32; ++k)
    sc[k] = dot32r(&sk[k*132 + h*32], qreg) * 0.17677669529663687f;
  float mx = sc[0];
#pragma unroll
  for (int k = 1; k < 32; ++k) mx = fmaxf(mx, sc[k]);
  float se = 0.f;
#pragma unroll
  for (int k = 0; k < 32; ++k) { sc[k] = expf(sc[k] - mx); se += sc[k]; }
  const float inv = 1.f / se;

  __syncthreads();

  float od[32];
#pragma unroll
  for (int i = 0; i < 32; ++i) od[i] = 0.f;
#pragma unroll 4
  for (int k = 0; k < 32; ++k) {
    const float w = sc[k] * inv;
    const float* vr = &sv[k*132 + h*32];
#pragma unroll
    for (int i = 0; i < 32; i += 4) {
      float4 v = F4(&vr[i]);
      od[i]   = fmaf(w, v.x, od[i]);
      od[i+1] = fmaf(w, v.y, od[i+1]);
      od[i+2] = fmaf(w, v.z, od[i+2]);
      od[i+3] = fmaf(w, v.w, od[i+3]);
    }
  }
#pragma unroll
  for (int i = 0; i < 32; i += 4)
    *(float4*)&sk[qr*132 + h*32 + i] = make_float4(od[i], od[i+1], od[i+2], od[i+3]);
  __syncthreads();

  for (int idx = tid; idx < 1024; idx += 128) {
    const int a = idx >> 5, c4 = idx & 31;
    *(float4*)&dqkv[(size_t)(b*32+a)*384 + 256 + c4*4] = F4(&sk[a*132 + c4*4]);
  }
}

// ---------------- per-molecule pooling + proj; also scatter expl into COMB slices ----------------
__global__ __launch_bounds__(128) void pool_kernel(
    const float* __restrict__ att, const float* __restrict__ x,
    const float* __restrict__ pW, const float* __restrict__ pb,
    float* __restrict__ expl, float* __restrict__ lrn, float* __restrict__ comb)
{
  __shared__ float satt[32*132];
  __shared__ float sx[32*132];
  __shared__ float aw_l[32];
  __shared__ float spool[512];
  const int tid = threadIdx.x;
  const int b = blockIdx.x;

  for (int idx = tid; idx < 1024; idx += 128) {
    const int a = idx >> 5, c4 = idx & 31;
    *(float4*)&satt[a*132 + c4*4] = F4(&att[(size_t)(b*32+a)*128 + c4*4]);
    *(float4*)&sx[a*132 + c4*4]   = F4(&x[(size_t)(b*32+a)*128 + c4*4]);
  }
  __syncthreads();

  {
    const int a = tid >> 2, q4 = tid & 3;
    float sp = 0.f;
#pragma unroll
    for (int i = 0; i < 32; ++i)
      sp = fmaf(satt[a*132 + q4*32 + i], sx[a*132 + q4*32 + i], sp);
    sp += __shfl_xor(sp, 1);
    sp += __shfl_xor(sp, 2);
    if (q4 == 0) aw_l[a] = sp;
  }
  __syncthreads();

  {
    float awr[32];
    float mxl = aw_l[0];
#pragma unroll
    for (int a = 1; a < 32; ++a) mxl = fmaxf(mxl, aw_l[a]);
    float se = 0.f;
#pragma unroll
    for (int a = 0; a < 32; ++a) { awr[a] = expf(aw_l[a] - mxl); se += awr[a]; }
    const float inv = 1.f / se;
    const int c = tid;
    float mx = -3.4e38f, sm = 0.f, wm = 0.f, ex = 0.f;
#pragma unroll
    for (int a = 0; a < 32; ++a) {
      const float v = satt[a*132 + c];
      mx = fmaxf(mx, v);
      sm += v;
      wm = fmaf(v, awr[a], wm);
      ex += sx[a*132 + c];
    }
    wm *= inv;
    const float mean = sm * 0.03125f;
    float s2 = 0.f;
#pragma unroll
    for (int a = 0; a < 32; ++a) {
      const float d = satt[a*132 + c] - mean;
      s2 = fmaf(d, d, s2);
    }
    const float stdp = sqrtf(s2 * (1.f/31.f));  // ddof=1
    const float exm = ex * 0.03125f;
    expl[b*128 + c] = exm;
#pragma unroll
    for (int p = 0; p < 4; ++p)
      comb[(size_t)b*1024 + p*256 + c] = exm;
    spool[c]       = wm;
    spool[128 + c] = mx;
    spool[256 + c] = mean;
    spool[384 + c] = stdp;
  }
  __syncthreads();

  if (tid < 64) {
    const int k = tid >> 4, qq = tid & 15;
    const float* pk = pW + k*2048;
    float s0 = 0.f, s1 = 0.f, s2 = 0.f, s3 = 0.f;
    for (int h2 = 0; h2 < 128; h2 += 4) {
      s0 = fmaf(spool[k*128 + h2],   pk[h2*16 + qq],     s0);
      s1 = fmaf(spool[k*128 + h2+1], pk[(h2+1)*16 + qq], s1);
      s2 = fmaf(spool[k*128 + h2+2], pk[(h2+2)*16 + qq], s2);
      s3 = fmaf(spool[k*128 + h2+3], pk[(h2+3)*16 + qq], s3);
    }
    lrn[b*64 + tid] = pb[k*16 + qq] + (s0+s1) + (s2+s3);
  }
}

// ---------------- molf pad to [1024, 224] ----------------
__global__ __launch_bounds__(256) void padmolf_kernel(
    const float* __restrict__ molf, float* __restrict__ mp)
{
  const int i = blockIdx.x*256 + threadIdx.x;  // 1024*224
  const int b = i / 224, m = i - b*224;
  mp[i] = (m < 200) ? molf[b*200 + m] : 0.f;
}

// ---------------- final dot: out[p][b] = H1[b, p*32..]·hW2[p] + hb2[p] ----------------
__global__ __launch_bounds__(256) void outdot_kernel(
    const float* __restrict__ H1, const float* __restrict__ hW2,
    const float* __restrict__ hb2, float* __restrict__ out)
{
  const int id = blockIdx.x*256 + threadIdx.x;  // 4096
  const int b = id & 1023, p = id >> 10;
  const float* hp = &H1[(size_t)b*128 + p*32];
  const float* wp = &hW2[p*32];
  float s0=0.f,s1=0.f,s2=0.f,s3=0.f;
  for (int h = 0; h < 32; h += 4) {
    s0 = fmaf(hp[h],   wp[h],   s0);
    s1 = fmaf(hp[h+1], wp[h+1], s1);
    s2 = fmaf(hp[h+2], wp[h+2], s2);
    s3 = fmaf(hp[h+3], wp[h+3], s3);
  }
  out[p*1024 + b] = (s0+s1) + (s2+s3) + hb2[p];
}

extern "C" void kernel_launch(void* const* d_in, const int* in_sizes, int n_in,
                              void* d_out, int out_size, void* d_ws, size_t ws_size,
                              hipStream_t stream) {
  const float* x_atoms    = (const float*)d_in[0];
  const float* pos        = (const float*)d_in[1];
  const float* molf       = (const float*)d_in[3];
  const float* emb_W      = (const float*)d_in[4];
  const float* emb_b      = (const float*)d_in[5];
  const float* mp_W1      = (const float*)d_in[6];
  const float* mp_b1      = (const float*)d_in[7];
  const float* mp_W2      = (const float*)d_in[8];
  const float* mp_b2      = (const float*)d_in[9];
  const float* ln_g       = (const float*)d_in[10];
  const float* ln_b       = (const float*)d_in[11];
  const float* attn_in_w  = (const float*)d_in[12];
  const float* attn_in_b  = (const float*)d_in[13];
  const float* attn_out_w = (const float*)d_in[14];
  const float* attn_out_b = (const float*)d_in[15];
  const float* pool_W     = (const float*)d_in[16];
  const float* pool_b     = (const float*)d_in[17];
  const float* mol_gate   = (const float*)d_in[18];
  const float* lrn_gate   = (const float*)d_in[19];
  const float* meW1       = (const float*)d_in[20];
  const float* meb1       = (const float*)d_in[21];
  const float* meW2       = (const float*)d_in[22];
  const float* meb2       = (const float*)d_in[23];
  const float* leW1       = (const float*)d_in[24];
  const float* leb1       = (const float*)d_in[25];
  const float* leW2       = (const float*)d_in[26];
  const float* leb2       = (const float*)d_in[27];
  const float* fW1        = (const float*)d_in[28];
  const float* fb1        = (const float*)d_in[29];
  const float* fW2        = (const float*)d_in[30];
  const float* fb2        = (const float*)d_in[31];
  const float* hW1        = (const float*)d_in[32];
  const float* hb1        = (const float*)d_in[33];
  const float* hW2        = (const float*)d_in[34];
  const float* hb2        = (const float*)d_in[35];
  const int*   ei         = (const int*)d_in[36];

  float* ws      = (float*)d_ws;
  float* x       = ws;                              // NN*128
  float* region  = x + (size_t)NN*128;              // NN*384 floats
  float* P       = region;                          // NN*128 fp32
  unsigned short* Qbf = (unsigned short*)(region + (size_t)NN*128); // NN*128 bf16
  float* dqkv    = region;                          // NN*384 (layer bufs dead)
  float* att     = region + (size_t)NN*384;         // NN*128
  float* csr_rf  = att + (size_t)NN*128;            // NE*4 floats (float4 records)
  float4* csr_rec = (float4*)csr_rf;
  int*   cnt_i   = (int*)(csr_rf + (size_t)NE*4);   // NN
  int*   csr_off = cnt_i + NN;                      // NN+64 (padded)
  int*   cur     = csr_off + NN + 64;               // NN
  float* lrn     = (float*)(cur + NN);              // NB*64
  float* expl    = lrn + NB*64;                     // NB*128
  float* pqbias  = expl + NB*128;                   // 768
  short* bh      = (short*)(pqbias + 768);          // PK_TOTAL shorts
  short* bl      = bh + PK_TOTAL;                   // PK_TOTAL shorts

  // head intermediates (inside region; dqkv dead after attout)
  float* molfPad = region;                          // 1024*224
  float* MOLR1   = region + 229376;                 // 1024*256
  float* LRNR1   = region + 491520;                 // 1024*256
  float* COMB    = region + 753664;                 // 1024*1024
  float* FUS1    = region + 1802240;                // 1024*512
  float* FUS2    = region + 2326528;                // 1024*256
  float* H1      = region + 2588672;                // 1024*128

  hipMemsetAsync(cnt_i, 0, (size_t)NN*sizeof(int), stream);

  embed_kernel<<<NN, 128, 0, stream>>>(x_atoms, emb_W, emb_b, x);
  hist_kernel<<<NE/256, 256, 0, stream>>>(ei, cnt_i);
  scan_kernel<<<1, 1024, 0, stream>>>(cnt_i, csr_off, cur);
  scatter_kernel<<<NE/256, 256, 0, stream>>>(pos, ei, cur, csr_rec);
  prep_kernel<<<(PK_TOTAL + 255)/256, 256, 0, stream>>>(
      mp_W1, mp_W2, attn_in_w, attn_out_w, mp_b1,
      mol_gate, lrn_gate, meW1, meW2, leW1, leW2, fW1, fW2, hW1,
      bh, bl, pqbias);

  for (int l = 0; l < 3; ++l) {
    mfma_gemm_kernel<<<dim3(NN/128, 4), 256, 0, stream>>>(
        x, 128, 128, bh + W1AB_OFF + l*32768, bl + W1AB_OFF + l*32768,
        pqbias + l*256, P, 256, 128, 64, 0, 0, Qbf);
    agg_kernel<<<NN/4, 256, 0, stream>>>(P, Qbf, csr_off, csr_rec,
                                         mp_W1 + (size_t)l*259*128);
    mfma_gemm_ln_kernel<<<NN/64, 256, 0, stream>>>(
        P, 128, bh + W2_OFF + l*16384, bl + W2_OFF + l*16384,
        mp_b2 + l*128, csr_off, ln_g + l*128, ln_b + l*128, x);
  }

  // attention path
  mfma_gemm_kernel<<<dim3(NN/128, 6), 256, 0, stream>>>(
      x, 128, 128, bh + WIN_OFF, bl + WIN_OFF, attn_in_b, dqkv, 384, 384, 64, 0, 0, nullptr);
  attn_kernel<<<NB, 128, 0, stream>>>(dqkv);
  mfma_gemm_kernel<<<dim3(NN/128, 2), 256, 0, stream>>>(
      dqkv + 256, 384, 128, bh + WOUT_OFF, bl + WOUT_OFF, attn_out_b, att, 128, 128, 64, 0, 0, nullptr);
  pool_kernel<<<NB, 128, 0, stream>>>(att, x, pool_W, pool_b, expl, lrn, COMB);

  // head chain (M = 1024 molecules)
  padmolf_kernel<<<(1024*224)/256, 256, 0, stream>>>(molf, molfPad);
  mfma_gemm_kernel<<<dim3(8, 4), 256, 0, stream>>>(          // MOLR1 = relu(molfPad@WA+meb1)
      molfPad, 224, 224, bh + HA_OFF, bl + HA_OFF, meb1, MOLR1, 256, 256, 64, 0, 1, nullptr);
  mfma_gemm_kernel<<<dim3(8, 4), 256, 0, stream>>>(          // MOLR2 -> COMB[:,p*256+128+h]
      MOLR1, 256, 256, bh + HB_OFF, bl + HB_OFF, meb2, COMB, 256, 1024, 256, 128, 0, nullptr);
  mfma_gemm_kernel<<<dim3(8, 4), 256, 0, stream>>>(          // LRNR1 = relu(lrn@WL+leb1)
      lrn, 64, 64, bh + HL_OFF, bl + HL_OFF, leb1, LRNR1, 256, 256, 64, 0, 1, nullptr);
  mfma_gemm_kernel<<<dim3(8, 4), 256, 0, stream>>>(          // LRNR2 -> COMB[:,p*256+192+h]
      LRNR1, 256, 256, bh + HD_OFF, bl + HD_OFF, leb2, COMB, 256, 1024, 256, 192, 0, nullptr);
  mfma_gemm_kernel<<<dim3(8, 8), 256, 0, stream>>>(          // FUS1 = relu(COMB@WF1+fb1)
      COMB, 1024, 1024, bh + HF1_OFF, bl + HF1_OFF, fb1, FUS1, 512, 512, 64, 0, 1, nullptr);
  mfma_gemm_kernel<<<dim3(8, 4), 256, 0, stream>>>(          // FUS2 = FUS1@WF2+fb2
      FUS1, 512, 512, bh + HF2_OFF, bl + HF2_OFF, fb2, FUS2, 256, 256, 64, 0, 0, nullptr);
  mfma_gemm_kernel<<<dim3(8, 2), 256, 0, stream>>>(          // H1 = relu(FUS2@WH1+hb1)
      FUS2, 256, 256, bh + HH1_OFF, bl + HH1_OFF, hb1, H1, 128, 128, 64, 0, 1, nullptr);
  outdot_kernel<<<16, 256, 0, stream>>>(H1, hW2, hb2, (float*)d_out);
}

// Round 9
// 447.106 us; speedup vs baseline: 1.0568x; 1.0568x over previous
//
#include <hip/hip_runtime.h>

#define NE 524288
#define NN 32768
#define NB 1024

#define F4(p) (*(const float4*)(p))

typedef __bf16 bf16x8 __attribute__((ext_vector_type(8)));
typedef float  f32x4  __attribute__((ext_vector_type(4)));

__device__ __forceinline__ float sigmoidf_(float v) { return 1.f / (1.f + expf(-v)); }

__device__ __forceinline__ void bf16split(float f, short &hi, short &lo) {
  unsigned u = __float_as_uint(f);
  unsigned rh = (u + 0x7FFFu + ((u >> 16) & 1u)) >> 16;
  float fh = __uint_as_float(rh << 16);
  float fl = f - fh;
  unsigned u2 = __float_as_uint(fl);
  unsigned rl = (u2 + 0x7FFFu + ((u2 >> 16) & 1u)) >> 16;
  hi = (short)rh; lo = (short)rl;
}

__device__ __forceinline__ unsigned short f2bf(float f) {
  unsigned u = __float_as_uint(f);
  return (unsigned short)((u + 0x7FFFu + ((u >> 16) & 1u)) >> 16);
}
__device__ __forceinline__ float bf2f(unsigned short h) {
  return __uint_as_float(((unsigned)h) << 16);
}

__device__ __forceinline__ void ld32(float* xr, const float* p) {
#pragma unroll
  for (int i = 0; i < 32; i += 4) {
    float4 v = F4(&p[i]);
    xr[i] = v.x; xr[i+1] = v.y; xr[i+2] = v.z; xr[i+3] = v.w;
  }
}

__device__ __forceinline__ float dot32r(const float* __restrict__ w, const float* xr) {
  float s = 0.f;
#pragma unroll
  for (int i = 0; i < 32; i += 4) {
    float4 ww = F4(&w[i]);
    s = fmaf(xr[i],   ww.x, s);
    s = fmaf(xr[i+1], ww.y, s);
    s = fmaf(xr[i+2], ww.z, s);
    s = fmaf(xr[i+3], ww.w, s);
  }
  return s;
}

// ---------------- CSR build ----------------
__global__ __launch_bounds__(256) void hist_kernel(const int* __restrict__ ei, int* __restrict__ cnt) {
  const int e = blockIdx.x*256 + threadIdx.x;
  atomicAdd(&cnt[ei[NE + e]], 1);
}

__global__ __launch_bounds__(1024) void scan_kernel(
    const int* __restrict__ cnt, int* __restrict__ off, int* __restrict__ cur)
{
  __shared__ int wsum[16];
  const int t = threadIdx.x;
  int local[32];
  const int base = t*32;
  int s = 0;
#pragma unroll
  for (int i = 0; i < 32; ++i) { local[i] = cnt[base+i]; s += local[i]; }
  int pre = s;
  const int lane = t & 63;
#pragma unroll
  for (int o = 1; o < 64; o <<= 1) { int v = __shfl_up(pre, o); if (lane >= o) pre += v; }
  if (lane == 63) wsum[t >> 6] = pre;
  __syncthreads();
  if (t == 0) { int a = 0; for (int w = 0; w < 16; ++w) { int v = wsum[w]; wsum[w] = a; a += v; } }
  __syncthreads();
  int excl = wsum[t >> 6] + pre - s;
#pragma unroll
  for (int i = 0; i < 32; ++i) { off[base+i] = excl; cur[base+i] = excl; excl += local[i]; }
  if (t == 1023) off[NN] = excl;
}

// edge record: {src_as_float, d, 1/(1+d), exp(-d)}
__global__ __launch_bounds__(256) void scatter_kernel(
    const float* __restrict__ pos, const int* __restrict__ ei,
    int* __restrict__ cur, float4* __restrict__ csr_rec)
{
  const int e = blockIdx.x*256 + threadIdx.x;
  const int s = ei[e];
  const int d = ei[NE + e];
  float dx = pos[d*3+0] - pos[s*3+0];
  float dy = pos[d*3+1] - pos[s*3+1];
  float dz = pos[d*3+2] - pos[s*3+2];
  float dist = sqrtf(dx*dx + dy*dy + dz*dz + 1e-12f);
  const int slot = atomicAdd(&cur[d], 1);
  csr_rec[slot] = make_float4(__int_as_float(s), dist, 1.f/(1.f + dist), expf(-dist));
}

// ---------------- weight prep: split-bf16, MFMA-frag-major ----------------
__device__ __forceinline__ void pack_decode(int r, int N, int &k, int &n) {
  const int j = r & 7, lane = (r >> 3) & 63, rest = r >> 9;
  const int NT = N >> 4;
  const int t = rest % NT, kc = rest / NT;
  k = kc*32 + (lane >> 4)*8 + j;
  n = t*16 + (lane & 15);
}

// segment offsets (elements)
#define W1AB_OFF 0        // l*32768, K=128 N=256
#define W2_OFF   98304    // l*16384, K=128 N=128
#define WIN_OFF  147456   // K=128 N=384
#define WOUT_OFF 196608   // K=128 N=128
#define EMB_OFF  212992   // K=64  N=128
#define PK_TOTAL 221184

__global__ __launch_bounds__(256) void prep_kernel(
    const float* __restrict__ mp_W1, const float* __restrict__ mp_W2,
    const float* __restrict__ win, const float* __restrict__ wout,
    const float* __restrict__ emb_W, const float* __restrict__ mp_b1,
    short* __restrict__ bh, short* __restrict__ bl, float* __restrict__ pqbias)
{
  const int i = blockIdx.x*256 + threadIdx.x;
  if (i < 768) { const int l = i >> 8, t = i & 255; pqbias[i] = t < 128 ? mp_b1[l*128 + t] : 0.f; }
  if (i >= PK_TOTAL) return;
  int k, n; float v;
  if (i < W2_OFF) {
    const int l = i / 32768, r = i % 32768;
    pack_decode(r, 256, k, n);
    const float* W = mp_W1 + (size_t)l*259*128;
    v = (n < 128) ? W[k*128 + n] : W[(128+k)*128 + (n-128)];
  } else if (i < WIN_OFF) {
    const int q = i - W2_OFF, l = q / 16384, r = q % 16384;
    pack_decode(r, 128, k, n);
    v = mp_W2[(size_t)l*16384 + k*128 + n];
  } else if (i < WOUT_OFF) {
    pack_decode(i - WIN_OFF, 384, k, n);
    v = win[n*128 + k];
  } else if (i < EMB_OFF) {
    pack_decode(i - WOUT_OFF, 128, k, n);
    v = wout[n*128 + k];
  } else {
    pack_decode(i - EMB_OFF, 128, k, n);   // K=64 segment: k < 64 by construction
    v = emb_W[k*128 + n];
  }
  short h_, lo; bf16split(v, h_, lo);
  bh[i] = h_; bl[i] = lo;
}

// ---------------- generic MFMA GEMM: C[M][·] = op(A[M][K] @ B + bias) ----------------
// block = 4 waves; wave = 32 rows x 64 cols; grid = (M/128, ncols/64). split-bf16 3-term.
// If qbf != null, cols >= 128 go to qbf as bf16 (pq path).
__global__ __launch_bounds__(256, 2) void mfma_gemm_kernel(
    const float* __restrict__ A, int lda, int K,
    const short* __restrict__ Bh, const short* __restrict__ Bl,
    const float* __restrict__ bias, float* __restrict__ C, int ncols, int ldc,
    int relu, unsigned short* __restrict__ qbf)
{
  const int lane = threadIdx.x & 63, wid = threadIdx.x >> 6;
  const int m0 = blockIdx.x * 128 + wid * 32;
  const int n0 = blockIdx.y * 64;
  const int NT = ncols >> 4;
  const int cl = lane & 15, kg = lane >> 4;
  const int KC = K >> 5;

  f32x4 acc[2][4];
#pragma unroll
  for (int s = 0; s < 2; ++s)
#pragma unroll
    for (int t = 0; t < 4; ++t) acc[s][t] = (f32x4){0.f,0.f,0.f,0.f};

  for (int kc = 0; kc < KC; ++kc) {
    bf16x8 Ah[2], Al[2];
#pragma unroll
    for (int s = 0; s < 2; ++s) {
      const float* ap = &A[(size_t)(m0 + s*16 + cl)*lda + kc*32 + kg*8];
      const float4 f0 = F4(ap), f1 = F4(ap + 4);
      const float fv[8] = {f0.x,f0.y,f0.z,f0.w,f1.x,f1.y,f1.z,f1.w};
      union { short s[8]; bf16x8 b; } uh, ul;
#pragma unroll
      for (int j = 0; j < 8; ++j) bf16split(fv[j], uh.s[j], ul.s[j]);
      Ah[s] = uh.b; Al[s] = ul.b;
    }
    bf16x8 Bfh[4], Bfl[4];
#pragma unroll
    for (int t = 0; t < 4; ++t) {
      const size_t off = (((size_t)(kc*NT + (n0 >> 4) + t))*64 + lane)*8;
      Bfh[t] = *(const bf16x8*)&Bh[off];
      Bfl[t] = *(const bf16x8*)&Bl[off];
    }
#pragma unroll
    for (int s = 0; s < 2; ++s)
#pragma unroll
      for (int t = 0; t < 4; ++t)
        acc[s][t] = __builtin_amdgcn_mfma_f32_16x16x32_bf16(Ah[s], Bfh[t], acc[s][t], 0, 0, 0);
#pragma unroll
    for (int s = 0; s < 2; ++s)
#pragma unroll
      for (int t = 0; t < 4; ++t)
        acc[s][t] = __builtin_amdgcn_mfma_f32_16x16x32_bf16(Ah[s], Bfl[t], acc[s][t], 0, 0, 0);
#pragma unroll
    for (int s = 0; s < 2; ++s)
#pragma unroll
      for (int t = 0; t < 4; ++t)
        acc[s][t] = __builtin_amdgcn_mfma_f32_16x16x32_bf16(Al[s], Bfh[t], acc[s][t], 0, 0, 0);
  }

#pragma unroll
  for (int t = 0; t < 4; ++t) {
    const int col = n0 + t*16 + cl;
    const float bv = bias[col];
#pragma unroll
    for (int s = 0; s < 2; ++s) {
      const int rbase = m0 + s*16 + kg*4;
#pragma unroll
      for (int r = 0; r < 4; ++r) {
        float v = acc[s][t][r] + bv;
        if (relu) v = fmaxf(v, 0.f);
        if (qbf && col >= 128)
          qbf[(size_t)(rbase + r)*128 + (col - 128)] = f2bf(v);
        else
          C[(size_t)(rbase + r)*ldc + col] = v;
      }
    }
  }
}

// ---------------- MFMA GEMM + residual + LN ----------------
__global__ __launch_bounds__(256, 2) void mfma_gemm_ln_kernel(
    const float* __restrict__ A, int lda,
    const short* __restrict__ Bh, const short* __restrict__ Bl,
    const float* __restrict__ b2, const int* __restrict__ csr_off,
    const float* __restrict__ g, const float* __restrict__ bb,
    float* __restrict__ x)
{
  const int lane = threadIdx.x & 63, wid = threadIdx.x >> 6;
  const int m0 = blockIdx.x * 64 + wid * 16;
  const int cl = lane & 15, kg = lane >> 4;

  bf16x8 Ah[4], Al[4];
#pragma unroll
  for (int kc = 0; kc < 4; ++kc) {
    const float* ap = &A[(size_t)(m0 + cl)*lda + kc*32 + kg*8];
    const float4 f0 = F4(ap), f1 = F4(ap + 4);
    const float fv[8] = {f0.x,f0.y,f0.z,f0.w,f1.x,f1.y,f1.z,f1.w};
    union { short s[8]; bf16x8 b; } uh, ul;
#pragma unroll
    for (int j = 0; j < 8; ++j) bf16split(fv[j], uh.s[j], ul.s[j]);
    Ah[kc] = uh.b; Al[kc] = ul.b;
  }

  f32x4 acc[8];
#pragma unroll
  for (int t = 0; t < 8; ++t) acc[t] = (f32x4){0.f,0.f,0.f,0.f};

#pragma unroll
  for (int kc = 0; kc < 4; ++kc) {
    bf16x8 Bfh[8], Bfl[8];
#pragma unroll
    for (int t = 0; t < 8; ++t) {
      const size_t off = (((size_t)(kc*8 + t))*64 + lane)*8;
      Bfh[t] = *(const bf16x8*)&Bh[off];
      Bfl[t] = *(const bf16x8*)&Bl[off];
    }
#pragma unroll
    for (int t = 0; t < 8; ++t)
      acc[t] = __builtin_amdgcn_mfma_f32_16x16x32_bf16(Ah[kc], Bfh[t], acc[t], 0, 0, 0);
#pragma unroll
    for (int t = 0; t < 8; ++t)
      acc[t] = __builtin_amdgcn_mfma_f32_16x16x32_bf16(Ah[kc], Bfl[t], acc[t], 0, 0, 0);
#pragma unroll
    for (int t = 0; t < 8; ++t)
      acc[t] = __builtin_amdgcn_mfma_f32_16x16x32_bf16(Al[kc], Bfh[t], acc[t], 0, 0, 0);
  }

  const int r0 = m0 + kg*4;
  float sflag[4];
#pragma unroll
  for (int r = 0; r < 4; ++r)
    sflag[r] = (csr_off[r0 + r + 1] > csr_off[r0 + r]) ? 1.f : 0.f;

  float ps[4] = {0.f,0.f,0.f,0.f}, pq[4] = {0.f,0.f,0.f,0.f};
  float yv[8][4];
#pragma unroll
  for (int t = 0; t < 8; ++t) {
    const int col = t*16 + cl;
    const float b2v = b2[col];
#pragma unroll
    for (int r = 0; r < 4; ++r) {
      const float y = acc[t][r] + sflag[r]*b2v + x[(size_t)(r0 + r)*128 + col];
      yv[t][r] = y;
      ps[r] += y;
      pq[r] = fmaf(y, y, pq[r]);
    }
  }
#pragma unroll
  for (int o = 1; o < 16; o <<= 1) {
#pragma unroll
    for (int r = 0; r < 4; ++r) { ps[r] += __shfl_xor(ps[r], o); pq[r] += __shfl_xor(pq[r], o); }
  }
#pragma unroll
  for (int r = 0; r < 4; ++r) {
    const float mu = ps[r] * (1.f/128.f);
    const float var = pq[r]*(1.f/128.f) - mu*mu;
    const float rstd = rsqrtf(var + 1e-5f);
#pragma unroll
    for (int t = 0; t < 8; ++t) {
      const int col = t*16 + cl;
      x[(size_t)(r0 + r)*128 + col] = (yv[t][r] - mu)*rstd*g[col] + bb[col];
    }
  }
}

// ---------------- aggregation: P[n] <- mean_e relu(P[n]+Qbf[src]+df@W1c) ----------------
__global__ __launch_bounds__(256, 6) void agg_kernel(
    float* __restrict__ P, const unsigned short* __restrict__ Qbf,
    const int* __restrict__ csr_off, const float4* __restrict__ csr_rec,
    const float* __restrict__ W1)
{
  const int tid = threadIdx.x;
  const int node = blockIdx.x*4 + (tid >> 6);
  const int lane = tid & 63;
  const int c0 = lane*2;
  const int off0 = csr_off[node], off1 = csr_off[node+1];

  const float* __restrict__ w1c = W1 + 256*128;
  const float w00 = w1c[c0],       w01 = w1c[c0+1];
  const float w10 = w1c[128+c0],   w11 = w1c[128+c0+1];
  const float w20 = w1c[256+c0],   w21 = w1c[256+c0+1];
  const float2 p = *(const float2*)&P[(size_t)node*128 + c0];

  float a0 = 0.f, a1 = 0.f;
  int e = off0;
  for (; e + 8 <= off1; e += 8) {
    float4 rc[8];
#pragma unroll
    for (int j = 0; j < 8; ++j) rc[j] = csr_rec[e+j];
    ushort2 qv[8];
#pragma unroll
    for (int j = 0; j < 8; ++j)
      qv[j] = *(const ushort2*)&Qbf[(size_t)__float_as_int(rc[j].x)*128 + c0];
#pragma unroll
    for (int j = 0; j < 8; ++j) {
      float h0 = p.x + bf2f(qv[j].x);
      h0 = fmaf(rc[j].y, w00, h0); h0 = fmaf(rc[j].z, w10, h0); h0 = fmaf(rc[j].w, w20, h0);
      float h1 = p.y + bf2f(qv[j].y);
      h1 = fmaf(rc[j].y, w01, h1); h1 = fmaf(rc[j].z, w11, h1); h1 = fmaf(rc[j].w, w21, h1);
      a0 += fmaxf(h0, 0.f);
      a1 += fmaxf(h1, 0.f);
    }
  }
  for (; e < off1; ++e) {
    const float4 rc = csr_rec[e];
    const ushort2 qv = *(const ushort2*)&Qbf[(size_t)__float_as_int(rc.x)*128 + c0];
    float h0 = p.x + bf2f(qv.x);
    h0 = fmaf(rc.y, w00, h0); h0 = fmaf(rc.z, w10, h0); h0 = fmaf(rc.w, w20, h0);
    float h1 = p.y + bf2f(qv.y);
    h1 = fmaf(rc.y, w01, h1); h1 = fmaf(rc.z, w11, h1); h1 = fmaf(rc.w, w21, h1);
    a0 += fmaxf(h0, 0.f);
    a1 += fmaxf(h1, 0.f);
  }
  const int deg = off1 - off0;
  const float rc_ = deg > 0 ? 1.f/(float)deg : 1.f;
  *(float2*)&P[(size_t)node*128 + c0] = make_float2(a0*rc_, a1*rc_);
}

// ---------------- per-molecule attention on dqkv[n][384]; O -> dv slot ----------------
__global__ __launch_bounds__(128) void attn_kernel(float* __restrict__ dqkv)
{
  __shared__ float sk[32*132];
  __shared__ float sv[32*132];
  const int tid = threadIdx.x;
  const int b = blockIdx.x;

  for (int idx = tid; idx < 1024; idx += 128) {
    const int a = idx >> 5, c4 = idx & 31;
    *(float4*)&sk[a*132 + c4*4] = F4(&dqkv[(size_t)(b*32+a)*384 + 128 + c4*4]);
    *(float4*)&sv[a*132 + c4*4] = F4(&dqkv[(size_t)(b*32+a)*384 + 256 + c4*4]);
  }
  __syncthreads();

  const int h = tid >> 5, qr = tid & 31;
  float qreg[32];
  ld32(qreg, &dqkv[(size_t)(b*32+qr)*384 + h*32]);

  float sc[32];
#pragma unroll
  for (int k = 0; k < 32; ++k)
    sc[k] = dot32r(&sk[k*132 + h*32], qreg) * 0.17677669529663687f;
  float mx = sc[0];
#pragma unroll
  for (int k = 1; k < 32; ++k) mx = fmaxf(mx, sc[k]);
  float se = 0.f;
#pragma unroll
  for (int k = 0; k < 32; ++k) { sc[k] = expf(sc[k] - mx); se += sc[k]; }
  const float inv = 1.f / se;

  __syncthreads();

  float od[32];
#pragma unroll
  for (int i = 0; i < 32; ++i) od[i] = 0.f;
#pragma unroll 4
  for (int k = 0; k < 32; ++k) {
    const float w = sc[k] * inv;
    const float* vr = &sv[k*132 + h*32];
#pragma unroll
    for (int i = 0; i < 32; i += 4) {
      float4 v = F4(&vr[i]);
      od[i]   = fmaf(w, v.x, od[i]);
      od[i+1] = fmaf(w, v.y, od[i+1]);
      od[i+2] = fmaf(w, v.z, od[i+2]);
      od[i+3] = fmaf(w, v.w, od[i+3]);
    }
  }
#pragma unroll
  for (int i = 0; i < 32; i += 4)
    *(float4*)&sk[qr*132 + h*32 + i] = make_float4(od[i], od[i+1], od[i+2], od[i+3]);
  __syncthreads();

  for (int idx = tid; idx < 1024; idx += 128) {
    const int a = idx >> 5, c4 = idx & 31;
    *(float4*)&dqkv[(size_t)(b*32+a)*384 + 256 + c4*4] = F4(&sk[a*132 + c4*4]);
  }
}

// ---------------- per-molecule pooling + proj ----------------
__global__ __launch_bounds__(128) void pool_kernel(
    const float* __restrict__ att, const float* __restrict__ x,
    const float* __restrict__ pW, const float* __restrict__ pb,
    float* __restrict__ expl, float* __restrict__ lrn)
{
  __shared__ float satt[32*132];
  __shared__ float sx[32*132];
  __shared__ float aw_l[32];
  __shared__ float spool[512];
  const int tid = threadIdx.x;
  const int b = blockIdx.x;

  for (int idx = tid; idx < 1024; idx += 128) {
    const int a = idx >> 5, c4 = idx & 31;
    *(float4*)&satt[a*132 + c4*4] = F4(&att[(size_t)(b*32+a)*128 + c4*4]);
    *(float4*)&sx[a*132 + c4*4]   = F4(&x[(size_t)(b*32+a)*128 + c4*4]);
  }
  __syncthreads();

  {
    const int a = tid >> 2, q4 = tid & 3;
    float sp = 0.f;
#pragma unroll
    for (int i = 0; i < 32; ++i)
      sp = fmaf(satt[a*132 + q4*32 + i], sx[a*132 + q4*32 + i], sp);
    sp += __shfl_xor(sp, 1);
    sp += __shfl_xor(sp, 2);
    if (q4 == 0) aw_l[a] = sp;
  }
  __syncthreads();

  {
    float awr[32];
    float mxl = aw_l[0];
#pragma unroll
    for (int a = 1; a < 32; ++a) mxl = fmaxf(mxl, aw_l[a]);
    float se = 0.f;
#pragma unroll
    for (int a = 0; a < 32; ++a) { awr[a] = expf(aw_l[a] - mxl); se += awr[a]; }
    const float inv = 1.f / se;
    const int c = tid;
    float mx = -3.4e38f, sm = 0.f, wm = 0.f, ex = 0.f;
#pragma unroll
    for (int a = 0; a < 32; ++a) {
      const float v = satt[a*132 + c];
      mx = fmaxf(mx, v);
      sm += v;
      wm = fmaf(v, awr[a], wm);
      ex += sx[a*132 + c];
    }
    wm *= inv;
    const float mean = sm * 0.03125f;
    float s2 = 0.f;
#pragma unroll
    for (int a = 0; a < 32; ++a) {
      const float d = satt[a*132 + c] - mean;
      s2 = fmaf(d, d, s2);
    }
    const float stdp = sqrtf(s2 * (1.f/31.f));  // ddof=1
    expl[b*128 + c] = ex * 0.03125f;
    spool[c]       = wm;
    spool[128 + c] = mx;
    spool[256 + c] = mean;
    spool[384 + c] = stdp;
  }
  __syncthreads();

  if (tid < 64) {
    const int k = tid >> 4, qq = tid & 15;
    const float* pk = pW + k*2048;
    float s0 = 0.f, s1 = 0.f, s2 = 0.f, s3 = 0.f;
    for (int h2 = 0; h2 < 128; h2 += 4) {
      s0 = fmaf(spool[k*128 + h2],   pk[h2*16 + qq],     s0);
      s1 = fmaf(spool[k*128 + h2+1], pk[(h2+1)*16 + qq], s1);
      s2 = fmaf(spool[k*128 + h2+2], pk[(h2+2)*16 + qq], s2);
      s3 = fmaf(spool[k*128 + h2+3], pk[(h2+3)*16 + qq], s3);
    }
    lrn[b*64 + tid] = pb[k*16 + qq] + (s0+s1) + (s2+s3);
  }
}

// ---------------- fused head: block = (32 molecules, 1 property), grid (32, 4) ----------------
// All stages in LDS (rows padded to kill bank conflicts); weights dense per-p from L2.
__global__ __launch_bounds__(256) void fused_head_kernel(
    const float* __restrict__ molf, const float* __restrict__ lrn,
    const float* __restrict__ expl,
    const float* __restrict__ mol_gate, const float* __restrict__ lrn_gate,
    const float* __restrict__ meW1, const float* __restrict__ meb1,
    const float* __restrict__ meW2, const float* __restrict__ meb2,
    const float* __restrict__ leW1, const float* __restrict__ leb1,
    const float* __restrict__ leW2, const float* __restrict__ leb2,
    const float* __restrict__ fW1, const float* __restrict__ fb1,
    const float* __restrict__ fW2, const float* __restrict__ fb2,
    const float* __restrict__ hW1, const float* __restrict__ hb1,
    const float* __restrict__ hW2, const float* __restrict__ hb2,
    float* __restrict__ out)
{
  const int p  = blockIdx.y;
  const int b0 = blockIdx.x * 32;
  const int t  = threadIdx.x;
  const int m  = t >> 3, hg = t & 7;   // 32 molecules x 8 col-groups

  __shared__ float sgm[32][201];
  __shared__ float sgl[32][65];
  __shared__ float smr[32][65];
  __shared__ float slr[32][65];
  __shared__ float scomb[32][257];
  __shared__ float sf1[32][129];
  __shared__ float sf2[32][65];

  for (int i = t; i < 32*200; i += 256) {
    const int mm = i / 200, k = i - mm*200;
    sgm[mm][k] = molf[(size_t)(b0+mm)*200 + k] * sigmoidf_(mol_gate[p*200 + k]);
  }
  for (int i = t; i < 32*64; i += 256) {
    const int mm = i >> 6, k = i & 63;
    sgl[mm][k] = lrn[(size_t)(b0+mm)*64 + k] * sigmoidf_(lrn_gate[p*64 + k]);
  }
  for (int i = t; i < 32*128; i += 256) {
    const int mm = i >> 7, c = i & 127;
    scomb[mm][c] = expl[(size_t)(b0+mm)*128 + c];
  }
  __syncthreads();

  { // molr1 = relu(sgm @ meW1_p + meb1_p)  [32,64], K=200
    const float* w = meW1 + p*12800;
    const int h0 = hg*8;
    float acc[8] = {0.f,0.f,0.f,0.f,0.f,0.f,0.f,0.f};
    for (int k = 0; k < 200; ++k) {
      const float a = sgm[m][k];
      const float4 w0 = F4(&w[k*64 + h0]);
      const float4 w1 = F4(&w[k*64 + h0 + 4]);
      acc[0] = fmaf(a, w0.x, acc[0]); acc[1] = fmaf(a, w0.y, acc[1]);
      acc[2] = fmaf(a, w0.z, acc[2]); acc[3] = fmaf(a, w0.w, acc[3]);
      acc[4] = fmaf(a, w1.x, acc[4]); acc[5] = fmaf(a, w1.y, acc[5]);
      acc[6] = fmaf(a, w1.z, acc[6]); acc[7] = fmaf(a, w1.w, acc[7]);
    }
#pragma unroll
    for (int j = 0; j < 8; ++j)
      smr[m][h0+j] = fmaxf(acc[j] + meb1[p*64 + h0 + j], 0.f);
  }
  { // lrnr1 = relu(sgl @ leW1_p + leb1_p)  [32,64], K=64
    const float* w = leW1 + p*4096;
    const int h0 = hg*8;
    float acc[8] = {0.f,0.f,0.f,0.f,0.f,0.f,0.f,0.f};
    for (int k = 0; k < 64; ++k) {
      const float a = sgl[m][k];
      const float4 w0 = F4(&w[k*64 + h0]);
      const float4 w1 = F4(&w[k*64 + h0 + 4]);
      acc[0] = fmaf(a, w0.x, acc[0]); acc[1] = fmaf(a, w0.y, acc[1]);
      acc[2] = fmaf(a, w0.z, acc[2]); acc[3] = fmaf(a, w0.w, acc[3]);
      acc[4] = fmaf(a, w1.x, acc[4]); acc[5] = fmaf(a, w1.y, acc[5]);
      acc[6] = fmaf(a, w1.z, acc[6]); acc[7] = fmaf(a, w1.w, acc[7]);
    }
#pragma unroll
    for (int j = 0; j < 8; ++j)
      slr[m][h0+j] = fmaxf(acc[j] + leb1[p*64 + h0 + j], 0.f);
  }
  __syncthreads();

  { // molr2 -> scomb[:,128+h]; lrnr2 -> scomb[:,192+h]  (K=64 each)
    const float* w  = meW2 + p*4096;
    const float* w2 = leW2 + p*4096;
    const int h0 = hg*8;
    float acc[8] = {0.f,0.f,0.f,0.f,0.f,0.f,0.f,0.f};
    float bcc[8] = {0.f,0.f,0.f,0.f,0.f,0.f,0.f,0.f};
    for (int k = 0; k < 64; ++k) {
      const float a = smr[m][k];
      const float b = slr[m][k];
      const float4 w0 = F4(&w[k*64 + h0]);
      const float4 w1 = F4(&w[k*64 + h0 + 4]);
      const float4 v0 = F4(&w2[k*64 + h0]);
      const float4 v1 = F4(&w2[k*64 + h0 + 4]);
      acc[0] = fmaf(a, w0.x, acc[0]); acc[1] = fmaf(a, w0.y, acc[1]);
      acc[2] = fmaf(a, w0.z, acc[2]); acc[3] = fmaf(a, w0.w, acc[3]);
      acc[4] = fmaf(a, w1.x, acc[4]); acc[5] = fmaf(a, w1.y, acc[5]);
      acc[6] = fmaf(a, w1.z, acc[6]); acc[7] = fmaf(a, w1.w, acc[7]);
      bcc[0] = fmaf(b, v0.x, bcc[0]); bcc[1] = fmaf(b, v0.y, bcc[1]);
      bcc[2] = fmaf(b, v0.z, bcc[2]); bcc[3] = fmaf(b, v0.w, bcc[3]);
      bcc[4] = fmaf(b, v1.x, bcc[4]); bcc[5] = fmaf(b, v1.y, bcc[5]);
      bcc[6] = fmaf(b, v1.z, bcc[6]); bcc[7] = fmaf(b, v1.w, bcc[7]);
    }
#pragma unroll
    for (int j = 0; j < 8; ++j) {
      scomb[m][128 + h0 + j] = acc[j] + meb2[p*64 + h0 + j];
      scomb[m][192 + h0 + j] = bcc[j] + leb2[p*64 + h0 + j];
    }
  }
  __syncthreads();

  { // fus1 = relu(scomb @ fW1_p + fb1_p)  [32,128], K=256, 16 cols/thread
    const float* w = fW1 + p*32768;
    const int h0 = hg*16;
    float acc[16];
#pragma unroll
    for (int j = 0; j < 16; ++j) acc[j] = 0.f;
    for (int k = 0; k < 256; ++k) {
      const float a = scomb[m][k];
      const float* wp = &w[k*128 + h0];
#pragma unroll
      for (int j = 0; j < 16; j += 4) {
        const float4 wv = F4(&wp[j]);
        acc[j]   = fmaf(a, wv.x, acc[j]);
        acc[j+1] = fmaf(a, wv.y, acc[j+1]);
        acc[j+2] = fmaf(a, wv.z, acc[j+2]);
        acc[j+3] = fmaf(a, wv.w, acc[j+3]);
      }
    }
#pragma unroll
    for (int j = 0; j < 16; ++j)
      sf1[m][h0+j] = fmaxf(acc[j] + fb1[p*128 + h0 + j], 0.f);
  }
  __syncthreads();

  { // fus2 = sf1 @ fW2_p + fb2_p  [32,64], K=128
    const float* w = fW2 + p*8192;
    const int h0 = hg*8;
    float acc[8] = {0.f,0.f,0.f,0.f,0.f,0.f,0.f,0.f};
    for (int k = 0; k < 128; ++k) {
      const float a = sf1[m][k];
      const float4 w0 = F4(&w[k*64 + h0]);
      const float4 w1 = F4(&w[k*64 + h0 + 4]);
      acc[0] = fmaf(a, w0.x, acc[0]); acc[1] = fmaf(a, w0.y, acc[1]);
      acc[2] = fmaf(a, w0.z, acc[2]); acc[3] = fmaf(a, w0.w, acc[3]);
      acc[4] = fmaf(a, w1.x, acc[4]); acc[5] = fmaf(a, w1.y, acc[5]);
      acc[6] = fmaf(a, w1.z, acc[6]); acc[7] = fmaf(a, w1.w, acc[7]);
    }
#pragma unroll
    for (int j = 0; j < 8; ++j)
      sf2[m][h0+j] = acc[j] + fb2[p*64 + h0 + j];
  }
  __syncthreads();

  { // h1 = relu(sf2 @ hW1_p + hb1_p) [32,32]; dot with hW2_p; reduce over hg
    const float* w = hW1 + p*2048;
    const int h0 = hg*4;
    float acc[4] = {0.f,0.f,0.f,0.f};
    for (int k = 0; k < 64; ++k) {
      const float a = sf2[m][k];
      const float4 w0 = F4(&w[k*32 + h0]);
      acc[0] = fmaf(a, w0.x, acc[0]); acc[1] = fmaf(a, w0.y, acc[1]);
      acc[2] = fmaf(a, w0.z, acc[2]); acc[3] = fmaf(a, w0.w, acc[3]);
    }
    float val = 0.f;
#pragma unroll
    for (int j = 0; j < 4; ++j)
      val = fmaf(fmaxf(acc[j] + hb1[p*32 + h0 + j], 0.f), hW2[p*32 + h0 + j], val);
    val += __shfl_xor(val, 1);
    val += __shfl_xor(val, 2);
    val += __shfl_xor(val, 4);
    if (hg == 0) out[p*1024 + b0 + m] = val + hb2[p];
  }
}

extern "C" void kernel_launch(void* const* d_in, const int* in_sizes, int n_in,
                              void* d_out, int out_size, void* d_ws, size_t ws_size,
                              hipStream_t stream) {
  const float* x_atoms    = (const float*)d_in[0];
  const float* pos        = (const float*)d_in[1];
  const float* molf       = (const float*)d_in[3];
  const float* emb_W      = (const float*)d_in[4];
  const float* emb_b      = (const float*)d_in[5];
  const float* mp_W1      = (const float*)d_in[6];
  const float* mp_b1      = (const float*)d_in[7];
  const float* mp_W2      = (const float*)d_in[8];
  const float* mp_b2      = (const float*)d_in[9];
  const float* ln_g       = (const float*)d_in[10];
  const float* ln_b       = (const float*)d_in[11];
  const float* attn_in_w  = (const float*)d_in[12];
  const float* attn_in_b  = (const float*)d_in[13];
  const float* attn_out_w = (const float*)d_in[14];
  const float* attn_out_b = (const float*)d_in[15];
  const float* pool_W     = (const float*)d_in[16];
  const float* pool_b     = (const float*)d_in[17];
  const float* mol_gate   = (const float*)d_in[18];
  const float* lrn_gate   = (const float*)d_in[19];
  const float* meW1       = (const float*)d_in[20];
  const float* meb1       = (const float*)d_in[21];
  const float* meW2       = (const float*)d_in[22];
  const float* meb2       = (const float*)d_in[23];
  const float* leW1       = (const float*)d_in[24];
  const float* leb1       = (const float*)d_in[25];
  const float* leW2       = (const float*)d_in[26];
  const float* leb2       = (const float*)d_in[27];
  const float* fW1        = (const float*)d_in[28];
  const float* fb1        = (const float*)d_in[29];
  const float* fW2        = (const float*)d_in[30];
  const float* fb2        = (const float*)d_in[31];
  const float* hW1        = (const float*)d_in[32];
  const float* hb1        = (const float*)d_in[33];
  const float* hW2        = (const float*)d_in[34];
  const float* hb2        = (const float*)d_in[35];
  const int*   ei         = (const int*)d_in[36];

  float* ws      = (float*)d_ws;
  float* x       = ws;                              // NN*128
  float* region  = x + (size_t)NN*128;              // NN*384 floats
  float* P       = region;                          // NN*128 fp32
  unsigned short* Qbf = (unsigned short*)(region + (size_t)NN*128); // NN*128 bf16
  float* dqkv    = region;                          // NN*384 (layer bufs dead)
  float* att     = region + (size_t)NN*384;         // NN*128
  float* csr_rf  = att + (size_t)NN*128;            // NE*4 floats (float4 records)
  float4* csr_rec = (float4*)csr_rf;
  int*   cnt_i   = (int*)(csr_rf + (size_t)NE*4);   // NN
  int*   csr_off = cnt_i + NN;                      // NN+64 (padded)
  int*   cur     = csr_off + NN + 64;               // NN
  float* lrn     = (float*)(cur + NN);              // NB*64
  float* expl    = lrn + NB*64;                     // NB*128
  float* pqbias  = expl + NB*128;                   // 768
  short* bh      = (short*)(pqbias + 768);          // PK_TOTAL shorts
  short* bl      = bh + PK_TOTAL;                   // PK_TOTAL shorts

  hipMemsetAsync(cnt_i, 0, (size_t)NN*sizeof(int), stream);

  prep_kernel<<<(PK_TOTAL + 255)/256, 256, 0, stream>>>(
      mp_W1, mp_W2, attn_in_w, attn_out_w, emb_W, mp_b1, bh, bl, pqbias);
  hist_kernel<<<NE/256, 256, 0, stream>>>(ei, cnt_i);
  scan_kernel<<<1, 1024, 0, stream>>>(cnt_i, csr_off, cur);
  scatter_kernel<<<NE/256, 256, 0, stream>>>(pos, ei, cur, csr_rec);

  // embed via MFMA: x = x_atoms @ emb_W + emb_b
  mfma_gemm_kernel<<<dim3(NN/128, 2), 256, 0, stream>>>(
      x_atoms, 64, 64, bh + EMB_OFF, bl + EMB_OFF, emb_b, x, 128, 128, 0, nullptr);

  for (int l = 0; l < 3; ++l) {
    mfma_gemm_kernel<<<dim3(NN/128, 4), 256, 0, stream>>>(
        x, 128, 128, bh + W1AB_OFF + l*32768, bl + W1AB_OFF + l*32768,
        pqbias + l*256, P, 256, 128, 0, Qbf);
    agg_kernel<<<NN/4, 256, 0, stream>>>(P, Qbf, csr_off, csr_rec,
                                         mp_W1 + (size_t)l*259*128);
    mfma_gemm_ln_kernel<<<NN/64, 256, 0, stream>>>(
        P, 128, bh + W2_OFF + l*16384, bl + W2_OFF + l*16384,
        mp_b2 + l*128, csr_off, ln_g + l*128, ln_b + l*128, x);
  }

  // attention path
  mfma_gemm_kernel<<<dim3(NN/128, 6), 256, 0, stream>>>(
      x, 128, 128, bh + WIN_OFF, bl + WIN_OFF, attn_in_b, dqkv, 384, 384, 0, nullptr);
  attn_kernel<<<NB, 128, 0, stream>>>(dqkv);
  mfma_gemm_kernel<<<dim3(NN/128, 2), 256, 0, stream>>>(
      dqkv + 256, 384, 128, bh + WOUT_OFF, bl + WOUT_OFF, attn_out_b, att, 128, 128, 0, nullptr);
  pool_kernel<<<NB, 128, 0, stream>>>(att, x, pool_W, pool_b, expl, lrn);

  // fused per-property head
  fused_head_kernel<<<dim3(32, 4), 256, 0, stream>>>(
      molf, lrn, expl, mol_gate, lrn_gate,
      meW1, meb1, meW2, meb2, leW1, leb1, leW2, leb2,
      fW1, fb1, fW2, fb2, hW1, hb1, hW2, hb2, (float*)d_out);
}

// Round 10
// 432.908 us; speedup vs baseline: 1.0915x; 1.0328x over previous
//
#include <hip/hip_runtime.h>

#define NE 524288
#define NN 32768
#define NB 1024

#define F4(p) (*(const float4*)(p))

typedef __bf16 bf16x8 __attribute__((ext_vector_type(8)));
typedef float  f32x4  __attribute__((ext_vector_type(4)));

__device__ __forceinline__ float sigmoidf_(float v) { return 1.f / (1.f + expf(-v)); }

__device__ __forceinline__ void bf16split(float f, short &hi, short &lo) {
  unsigned u = __float_as_uint(f);
  unsigned rh = (u + 0x7FFFu + ((u >> 16) & 1u)) >> 16;
  float fh = __uint_as_float(rh << 16);
  float fl = f - fh;
  unsigned u2 = __float_as_uint(fl);
  unsigned rl = (u2 + 0x7FFFu + ((u2 >> 16) & 1u)) >> 16;
  hi = (short)rh; lo = (short)rl;
}

__device__ __forceinline__ unsigned short f2bf(float f) {
  unsigned u = __float_as_uint(f);
  return (unsigned short)((u + 0x7FFFu + ((u >> 16) & 1u)) >> 16);
}
__device__ __forceinline__ float bf2f(unsigned short h) {
  return __uint_as_float(((unsigned)h) << 16);
}

__device__ __forceinline__ void ld32(float* xr, const float* p) {
#pragma unroll
  for (int i = 0; i < 32; i += 4) {
    float4 v = F4(&p[i]);
    xr[i] = v.x; xr[i+1] = v.y; xr[i+2] = v.z; xr[i+3] = v.w;
  }
}

__device__ __forceinline__ float dot32r(const float* __restrict__ w, const float* xr) {
  float s = 0.f;
#pragma unroll
  for (int i = 0; i < 32; i += 4) {
    float4 ww = F4(&w[i]);
    s = fmaf(xr[i],   ww.x, s);
    s = fmaf(xr[i+1], ww.y, s);
    s = fmaf(xr[i+2], ww.z, s);
    s = fmaf(xr[i+3], ww.w, s);
  }
  return s;
}

// ---------------- CSR build ----------------
__global__ __launch_bounds__(256) void hist_kernel(const int* __restrict__ ei, int* __restrict__ cnt) {
  const int e = blockIdx.x*256 + threadIdx.x;
  atomicAdd(&cnt[ei[NE + e]], 1);
}

__global__ __launch_bounds__(1024) void scan_kernel(
    const int* __restrict__ cnt, int* __restrict__ off, int* __restrict__ cur)
{
  __shared__ int wsum[16];
  const int t = threadIdx.x;
  int local[32];
  const int base = t*32;
  int s = 0;
#pragma unroll
  for (int i = 0; i < 32; ++i) { local[i] = cnt[base+i]; s += local[i]; }
  int pre = s;
  const int lane = t & 63;
#pragma unroll
  for (int o = 1; o < 64; o <<= 1) { int v = __shfl_up(pre, o); if (lane >= o) pre += v; }
  if (lane == 63) wsum[t >> 6] = pre;
  __syncthreads();
  if (t == 0) { int a = 0; for (int w = 0; w < 16; ++w) { int v = wsum[w]; wsum[w] = a; a += v; } }
  __syncthreads();
  int excl = wsum[t >> 6] + pre - s;
#pragma unroll
  for (int i = 0; i < 32; ++i) { off[base+i] = excl; cur[base+i] = excl; excl += local[i]; }
  if (t == 1023) off[NN] = excl;
}

// edge record: {src_as_float, d, 1/(1+d), exp(-d)}
__global__ __launch_bounds__(256) void scatter_kernel(
    const float* __restrict__ pos, const int* __restrict__ ei,
    int* __restrict__ cur, float4* __restrict__ csr_rec)
{
  const int e = blockIdx.x*256 + threadIdx.x;
  const int s = ei[e];
  const int d = ei[NE + e];
  float dx = pos[d*3+0] - pos[s*3+0];
  float dy = pos[d*3+1] - pos[s*3+1];
  float dz = pos[d*3+2] - pos[s*3+2];
  float dist = sqrtf(dx*dx + dy*dy + dz*dz + 1e-12f);
  const int slot = atomicAdd(&cur[d], 1);
  csr_rec[slot] = make_float4(__int_as_float(s), dist, 1.f/(1.f + dist), expf(-dist));
}

// ---------------- weight prep: split-bf16, MFMA-frag-major ----------------
__device__ __forceinline__ void pack_decode(int r, int N, int &k, int &n) {
  const int j = r & 7, lane = (r >> 3) & 63, rest = r >> 9;
  const int NT = N >> 4;
  const int t = rest % NT, kc = rest / NT;
  k = kc*32 + (lane >> 4)*8 + j;
  n = t*16 + (lane & 15);
}

// segment offsets (elements)
#define W1AB_OFF 0        // l*32768, K=128 N=256
#define W2_OFF   98304    // l*16384, K=128 N=128
#define WIN_OFF  147456   // K=128 N=384
#define WOUT_OFF 196608   // K=128 N=128
#define EMB_OFF  212992   // K=64  N=128
#define PK_TOTAL 221184

__global__ __launch_bounds__(256) void prep_kernel(
    const float* __restrict__ mp_W1, const float* __restrict__ mp_W2,
    const float* __restrict__ win, const float* __restrict__ wout,
    const float* __restrict__ emb_W, const float* __restrict__ mp_b1,
    short* __restrict__ bh, short* __restrict__ bl, float* __restrict__ pqbias)
{
  const int i = blockIdx.x*256 + threadIdx.x;
  if (i < 768) { const int l = i >> 8, t = i & 255; pqbias[i] = t < 128 ? mp_b1[l*128 + t] : 0.f; }
  if (i >= PK_TOTAL) return;
  int k, n; float v;
  if (i < W2_OFF) {
    const int l = i / 32768, r = i % 32768;
    pack_decode(r, 256, k, n);
    const float* W = mp_W1 + (size_t)l*259*128;
    v = (n < 128) ? W[k*128 + n] : W[(128+k)*128 + (n-128)];
  } else if (i < WIN_OFF) {
    const int q = i - W2_OFF, l = q / 16384, r = q % 16384;
    pack_decode(r, 128, k, n);
    v = mp_W2[(size_t)l*16384 + k*128 + n];
  } else if (i < WOUT_OFF) {
    pack_decode(i - WIN_OFF, 384, k, n);
    v = win[n*128 + k];
  } else if (i < EMB_OFF) {
    pack_decode(i - WOUT_OFF, 128, k, n);
    v = wout[n*128 + k];
  } else {
    pack_decode(i - EMB_OFF, 128, k, n);   // K=64 segment: k < 64 by construction
    v = emb_W[k*128 + n];
  }
  short h_, lo; bf16split(v, h_, lo);
  bh[i] = h_; bl[i] = lo;
}

// ---------------- generic MFMA GEMM: C[M][·] = op(A[M][K] @ B + bias) ----------------
__global__ __launch_bounds__(256, 2) void mfma_gemm_kernel(
    const float* __restrict__ A, int lda, int K,
    const short* __restrict__ Bh, const short* __restrict__ Bl,
    const float* __restrict__ bias, float* __restrict__ C, int ncols, int ldc,
    int relu, unsigned short* __restrict__ qbf)
{
  const int lane = threadIdx.x & 63, wid = threadIdx.x >> 6;
  const int m0 = blockIdx.x * 128 + wid * 32;
  const int n0 = blockIdx.y * 64;
  const int NT = ncols >> 4;
  const int cl = lane & 15, kg = lane >> 4;
  const int KC = K >> 5;

  f32x4 acc[2][4];
#pragma unroll
  for (int s = 0; s < 2; ++s)
#pragma unroll
    for (int t = 0; t < 4; ++t) acc[s][t] = (f32x4){0.f,0.f,0.f,0.f};

  for (int kc = 0; kc < KC; ++kc) {
    bf16x8 Ah[2], Al[2];
#pragma unroll
    for (int s = 0; s < 2; ++s) {
      const float* ap = &A[(size_t)(m0 + s*16 + cl)*lda + kc*32 + kg*8];
      const float4 f0 = F4(ap), f1 = F4(ap + 4);
      const float fv[8] = {f0.x,f0.y,f0.z,f0.w,f1.x,f1.y,f1.z,f1.w};
      union { short s[8]; bf16x8 b; } uh, ul;
#pragma unroll
      for (int j = 0; j < 8; ++j) bf16split(fv[j], uh.s[j], ul.s[j]);
      Ah[s] = uh.b; Al[s] = ul.b;
    }
    bf16x8 Bfh[4], Bfl[4];
#pragma unroll
    for (int t = 0; t < 4; ++t) {
      const size_t off = (((size_t)(kc*NT + (n0 >> 4) + t))*64 + lane)*8;
      Bfh[t] = *(const bf16x8*)&Bh[off];
      Bfl[t] = *(const bf16x8*)&Bl[off];
    }
#pragma unroll
    for (int s = 0; s < 2; ++s)
#pragma unroll
      for (int t = 0; t < 4; ++t)
        acc[s][t] = __builtin_amdgcn_mfma_f32_16x16x32_bf16(Ah[s], Bfh[t], acc[s][t], 0, 0, 0);
#pragma unroll
    for (int s = 0; s < 2; ++s)
#pragma unroll
      for (int t = 0; t < 4; ++t)
        acc[s][t] = __builtin_amdgcn_mfma_f32_16x16x32_bf16(Ah[s], Bfl[t], acc[s][t], 0, 0, 0);
#pragma unroll
    for (int s = 0; s < 2; ++s)
#pragma unroll
      for (int t = 0; t < 4; ++t)
        acc[s][t] = __builtin_amdgcn_mfma_f32_16x16x32_bf16(Al[s], Bfh[t], acc[s][t], 0, 0, 0);
  }

#pragma unroll
  for (int t = 0; t < 4; ++t) {
    const int col = n0 + t*16 + cl;
    const float bv = bias[col];
#pragma unroll
    for (int s = 0; s < 2; ++s) {
      const int rbase = m0 + s*16 + kg*4;
#pragma unroll
      for (int r = 0; r < 4; ++r) {
        float v = acc[s][t][r] + bv;
        if (relu) v = fmaxf(v, 0.f);
        if (qbf && col >= 128)
          qbf[(size_t)(rbase + r)*128 + (col - 128)] = f2bf(v);
        else
          C[(size_t)(rbase + r)*ldc + col] = v;
      }
    }
  }
}

// ---------------- MFMA GEMM + residual + LN ----------------
__global__ __launch_bounds__(256, 2) void mfma_gemm_ln_kernel(
    const float* __restrict__ A, int lda,
    const short* __restrict__ Bh, const short* __restrict__ Bl,
    const float* __restrict__ b2, const int* __restrict__ csr_off,
    const float* __restrict__ g, const float* __restrict__ bb,
    float* __restrict__ x)
{
  const int lane = threadIdx.x & 63, wid = threadIdx.x >> 6;
  const int m0 = blockIdx.x * 64 + wid * 16;
  const int cl = lane & 15, kg = lane >> 4;

  bf16x8 Ah[4], Al[4];
#pragma unroll
  for (int kc = 0; kc < 4; ++kc) {
    const float* ap = &A[(size_t)(m0 + cl)*lda + kc*32 + kg*8];
    const float4 f0 = F4(ap), f1 = F4(ap + 4);
    const float fv[8] = {f0.x,f0.y,f0.z,f0.w,f1.x,f1.y,f1.z,f1.w};
    union { short s[8]; bf16x8 b; } uh, ul;
#pragma unroll
    for (int j = 0; j < 8; ++j) bf16split(fv[j], uh.s[j], ul.s[j]);
    Ah[kc] = uh.b; Al[kc] = ul.b;
  }

  f32x4 acc[8];
#pragma unroll
  for (int t = 0; t < 8; ++t) acc[t] = (f32x4){0.f,0.f,0.f,0.f};

#pragma unroll
  for (int kc = 0; kc < 4; ++kc) {
    bf16x8 Bfh[8], Bfl[8];
#pragma unroll
    for (int t = 0; t < 8; ++t) {
      const size_t off = (((size_t)(kc*8 + t))*64 + lane)*8;
      Bfh[t] = *(const bf16x8*)&Bh[off];
      Bfl[t] = *(const bf16x8*)&Bl[off];
    }
#pragma unroll
    for (int t = 0; t < 8; ++t)
      acc[t] = __builtin_amdgcn_mfma_f32_16x16x32_bf16(Ah[kc], Bfh[t], acc[t], 0, 0, 0);
#pragma unroll
    for (int t = 0; t < 8; ++t)
      acc[t] = __builtin_amdgcn_mfma_f32_16x16x32_bf16(Ah[kc], Bfl[t], acc[t], 0, 0, 0);
#pragma unroll
    for (int t = 0; t < 8; ++t)
      acc[t] = __builtin_amdgcn_mfma_f32_16x16x32_bf16(Al[kc], Bfh[t], acc[t], 0, 0, 0);
  }

  const int r0 = m0 + kg*4;
  float sflag[4];
#pragma unroll
  for (int r = 0; r < 4; ++r)
    sflag[r] = (csr_off[r0 + r + 1] > csr_off[r0 + r]) ? 1.f : 0.f;

  float ps[4] = {0.f,0.f,0.f,0.f}, pq[4] = {0.f,0.f,0.f,0.f};
  float yv[8][4];
#pragma unroll
  for (int t = 0; t < 8; ++t) {
    const int col = t*16 + cl;
    const float b2v = b2[col];
#pragma unroll
    for (int r = 0; r < 4; ++r) {
      const float y = acc[t][r] + sflag[r]*b2v + x[(size_t)(r0 + r)*128 + col];
      yv[t][r] = y;
      ps[r] += y;
      pq[r] = fmaf(y, y, pq[r]);
    }
  }
#pragma unroll
  for (int o = 1; o < 16; o <<= 1) {
#pragma unroll
    for (int r = 0; r < 4; ++r) { ps[r] += __shfl_xor(ps[r], o); pq[r] += __shfl_xor(pq[r], o); }
  }
#pragma unroll
  for (int r = 0; r < 4; ++r) {
    const float mu = ps[r] * (1.f/128.f);
    const float var = pq[r]*(1.f/128.f) - mu*mu;
    const float rstd = rsqrtf(var + 1e-5f);
#pragma unroll
    for (int t = 0; t < 8; ++t) {
      const int col = t*16 + cl;
      x[(size_t)(r0 + r)*128 + col] = (yv[t][r] - mu)*rstd*g[col] + bb[col];
    }
  }
}

// ---------------- aggregation: P[n] <- mean_e relu(P[n]+Qbf[src]+df@W1c) ----------------
__global__ __launch_bounds__(256, 6) void agg_kernel(
    float* __restrict__ P, const unsigned short* __restrict__ Qbf,
    const int* __restrict__ csr_off, const float4* __restrict__ csr_rec,
    const float* __restrict__ W1)
{
  const int tid = threadIdx.x;
  const int node = blockIdx.x*4 + (tid >> 6);
  const int lane = tid & 63;
  const int c0 = lane*2;
  const int off0 = csr_off[node], off1 = csr_off[node+1];

  const float* __restrict__ w1c = W1 + 256*128;
  const float w00 = w1c[c0],       w01 = w1c[c0+1];
  const float w10 = w1c[128+c0],   w11 = w1c[128+c0+1];
  const float w20 = w1c[256+c0],   w21 = w1c[256+c0+1];
  const float2 p = *(const float2*)&P[(size_t)node*128 + c0];

  float a0 = 0.f, a1 = 0.f;
  int e = off0;
  for (; e + 8 <= off1; e += 8) {
    float4 rc[8];
#pragma unroll
    for (int j = 0; j < 8; ++j) rc[j] = csr_rec[e+j];
    ushort2 qv[8];
#pragma unroll
    for (int j = 0; j < 8; ++j)
      qv[j] = *(const ushort2*)&Qbf[(size_t)__float_as_int(rc[j].x)*128 + c0];
#pragma unroll
    for (int j = 0; j < 8; ++j) {
      float h0 = p.x + bf2f(qv[j].x);
      h0 = fmaf(rc[j].y, w00, h0); h0 = fmaf(rc[j].z, w10, h0); h0 = fmaf(rc[j].w, w20, h0);
      float h1 = p.y + bf2f(qv[j].y);
      h1 = fmaf(rc[j].y, w01, h1); h1 = fmaf(rc[j].z, w11, h1); h1 = fmaf(rc[j].w, w21, h1);
      a0 += fmaxf(h0, 0.f);
      a1 += fmaxf(h1, 0.f);
    }
  }
  for (; e < off1; ++e) {
    const float4 rc = csr_rec[e];
    const ushort2 qv = *(const ushort2*)&Qbf[(size_t)__float_as_int(rc.x)*128 + c0];
    float h0 = p.x + bf2f(qv.x);
    h0 = fmaf(rc.y, w00, h0); h0 = fmaf(rc.z, w10, h0); h0 = fmaf(rc.w, w20, h0);
    float h1 = p.y + bf2f(qv.y);
    h1 = fmaf(rc.y, w01, h1); h1 = fmaf(rc.z, w11, h1); h1 = fmaf(rc.w, w21, h1);
    a0 += fmaxf(h0, 0.f);
    a1 += fmaxf(h1, 0.f);
  }
  const int deg = off1 - off0;
  const float rc_ = deg > 0 ? 1.f/(float)deg : 1.f;
  *(float2*)&P[(size_t)node*128 + c0] = make_float2(a0*rc_, a1*rc_);
}

// ---------------- per-molecule attention on dqkv[n][384]; O -> dv slot ----------------
__global__ __launch_bounds__(128) void attn_kernel(float* __restrict__ dqkv)
{
  __shared__ float sk[32*132];
  __shared__ float sv[32*132];
  const int tid = threadIdx.x;
  const int b = blockIdx.x;

  for (int idx = tid; idx < 1024; idx += 128) {
    const int a = idx >> 5, c4 = idx & 31;
    *(float4*)&sk[a*132 + c4*4] = F4(&dqkv[(size_t)(b*32+a)*384 + 128 + c4*4]);
    *(float4*)&sv[a*132 + c4*4] = F4(&dqkv[(size_t)(b*32+a)*384 + 256 + c4*4]);
  }
  __syncthreads();

  const int h = tid >> 5, qr = tid & 31;
  float qreg[32];
  ld32(qreg, &dqkv[(size_t)(b*32+qr)*384 + h*32]);

  float sc[32];
#pragma unroll
  for (int k = 0; k < 32; ++k)
    sc[k] = dot32r(&sk[k*132 + h*32], qreg) * 0.17677669529663687f;
  float mx = sc[0];
#pragma unroll
  for (int k = 1; k < 32; ++k) mx = fmaxf(mx, sc[k]);
  float se = 0.f;
#pragma unroll
  for (int k = 0; k < 32; ++k) { sc[k] = expf(sc[k] - mx); se += sc[k]; }
  const float inv = 1.f / se;

  __syncthreads();

  float od[32];
#pragma unroll
  for (int i = 0; i < 32; ++i) od[i] = 0.f;
#pragma unroll 4
  for (int k = 0; k < 32; ++k) {
    const float w = sc[k] * inv;
    const float* vr = &sv[k*132 + h*32];
#pragma unroll
    for (int i = 0; i < 32; i += 4) {
      float4 v = F4(&vr[i]);
      od[i]   = fmaf(w, v.x, od[i]);
      od[i+1] = fmaf(w, v.y, od[i+1]);
      od[i+2] = fmaf(w, v.z, od[i+2]);
      od[i+3] = fmaf(w, v.w, od[i+3]);
    }
  }
#pragma unroll
  for (int i = 0; i < 32; i += 4)
    *(float4*)&sk[qr*132 + h*32 + i] = make_float4(od[i], od[i+1], od[i+2], od[i+3]);
  __syncthreads();

  for (int idx = tid; idx < 1024; idx += 128) {
    const int a = idx >> 5, c4 = idx & 31;
    *(float4*)&dqkv[(size_t)(b*32+a)*384 + 256 + c4*4] = F4(&sk[a*132 + c4*4]);
  }
}

// ---------------- per-molecule pooling + proj ----------------
__global__ __launch_bounds__(128) void pool_kernel(
    const float* __restrict__ att, const float* __restrict__ x,
    const float* __restrict__ pW, const float* __restrict__ pb,
    float* __restrict__ expl, float* __restrict__ lrn)
{
  __shared__ float satt[32*132];
  __shared__ float sx[32*132];
  __shared__ float aw_l[32];
  __shared__ float spool[512];
  const int tid = threadIdx.x;
  const int b = blockIdx.x;

  for (int idx = tid; idx < 1024; idx += 128) {
    const int a = idx >> 5, c4 = idx & 31;
    *(float4*)&satt[a*132 + c4*4] = F4(&att[(size_t)(b*32+a)*128 + c4*4]);
    *(float4*)&sx[a*132 + c4*4]   = F4(&x[(size_t)(b*32+a)*128 + c4*4]);
  }
  __syncthreads();

  {
    const int a = tid >> 2, q4 = tid & 3;
    float sp = 0.f;
#pragma unroll
    for (int i = 0; i < 32; ++i)
      sp = fmaf(satt[a*132 + q4*32 + i], sx[a*132 + q4*32 + i], sp);
    sp += __shfl_xor(sp, 1);
    sp += __shfl_xor(sp, 2);
    if (q4 == 0) aw_l[a] = sp;
  }
  __syncthreads();

  {
    float awr[32];
    float mxl = aw_l[0];
#pragma unroll
    for (int a = 1; a < 32; ++a) mxl = fmaxf(mxl, aw_l[a]);
    float se = 0.f;
#pragma unroll
    for (int a = 0; a < 32; ++a) { awr[a] = expf(aw_l[a] - mxl); se += awr[a]; }
    const float inv = 1.f / se;
    const int c = tid;
    float mx = -3.4e38f, sm = 0.f, wm = 0.f, ex = 0.f;
#pragma unroll
    for (int a = 0; a < 32; ++a) {
      const float v = satt[a*132 + c];
      mx = fmaxf(mx, v);
      sm += v;
      wm = fmaf(v, awr[a], wm);
      ex += sx[a*132 + c];
    }
    wm *= inv;
    const float mean = sm * 0.03125f;
    float s2 = 0.f;
#pragma unroll
    for (int a = 0; a < 32; ++a) {
      const float d = satt[a*132 + c] - mean;
      s2 = fmaf(d, d, s2);
    }
    const float stdp = sqrtf(s2 * (1.f/31.f));  // ddof=1
    expl[b*128 + c] = ex * 0.03125f;
    spool[c]       = wm;
    spool[128 + c] = mx;
    spool[256 + c] = mean;
    spool[384 + c] = stdp;
  }
  __syncthreads();

  if (tid < 64) {
    const int k = tid >> 4, qq = tid & 15;
    const float* pk = pW + k*2048;
    float s0 = 0.f, s1 = 0.f, s2 = 0.f, s3 = 0.f;
    for (int h2 = 0; h2 < 128; h2 += 4) {
      s0 = fmaf(spool[k*128 + h2],   pk[h2*16 + qq],     s0);
      s1 = fmaf(spool[k*128 + h2+1], pk[(h2+1)*16 + qq], s1);
      s2 = fmaf(spool[k*128 + h2+2], pk[(h2+2)*16 + qq], s2);
      s3 = fmaf(spool[k*128 + h2+3], pk[(h2+3)*16 + qq], s3);
    }
    lrn[b*64 + tid] = pb[k*16 + qq] + (s0+s1) + (s2+s3);
  }
}

// ---------------- head: block = (4 molecules, 1 property), 64 threads, grid (256,4) ----------------
// Activations k-major in LDS ([k][4 mols] -> one broadcast ds_read_b128 feeds 4 FMAs);
// weight loads coalesced, amortized over 4 molecules (L2 traffic 4x lower than 1-mol/block).
__global__ __launch_bounds__(64) void head4_kernel(
    const float* __restrict__ molf, const float* __restrict__ lrn,
    const float* __restrict__ expl,
    const float* __restrict__ mol_gate, const float* __restrict__ lrn_gate,
    const float* __restrict__ meW1, const float* __restrict__ meb1,
    const float* __restrict__ meW2, const float* __restrict__ meb2,
    const float* __restrict__ leW1, const float* __restrict__ leb1,
    const float* __restrict__ leW2, const float* __restrict__ leb2,
    const float* __restrict__ fW1, const float* __restrict__ fb1,
    const float* __restrict__ fW2, const float* __restrict__ fb2,
    const float* __restrict__ hW1, const float* __restrict__ hb1,
    const float* __restrict__ hW2, const float* __restrict__ hb2,
    float* __restrict__ out)
{
  const int p = blockIdx.y, b0 = blockIdx.x*4, t = threadIdx.x;
  __shared__ float sgm[200*4];
  __shared__ float sgl[64*4];
  __shared__ float smr[64*4];
  __shared__ float slr[64*4];
  __shared__ float scomb[256*4];
  __shared__ float sf1[128*4];
  __shared__ float sf2[64*4];

  for (int i = t; i < 800; i += 64) {
    const int mm = i / 200, k = i - mm*200;
    sgm[k*4 + mm] = molf[(size_t)(b0+mm)*200 + k] * sigmoidf_(mol_gate[p*200 + k]);
  }
  for (int i = t; i < 256; i += 64) {
    const int mm = i >> 6, k = i & 63;
    sgl[k*4 + mm] = lrn[(size_t)(b0+mm)*64 + k] * sigmoidf_(lrn_gate[p*64 + k]);
  }
  for (int i = t; i < 512; i += 64) {
    const int c = i >> 2, mm = i & 3;
    scomb[i] = expl[(size_t)(b0+mm)*128 + c];
  }
  __syncthreads();

  { // molr1[4,64] = relu(sgm @ meW1_p + meb1_p); col = t, K=200
    const float* w = meW1 + p*12800 + t;
    float a0=0.f,a1=0.f,a2=0.f,a3=0.f;
#pragma unroll 4
    for (int k = 0; k < 200; ++k) {
      const float wv = w[k*64];
      const float4 a = F4(&sgm[k*4]);
      a0=fmaf(a.x,wv,a0); a1=fmaf(a.y,wv,a1); a2=fmaf(a.z,wv,a2); a3=fmaf(a.w,wv,a3);
    }
    const float b = meb1[p*64 + t];
    smr[t*4+0]=fmaxf(a0+b,0.f); smr[t*4+1]=fmaxf(a1+b,0.f);
    smr[t*4+2]=fmaxf(a2+b,0.f); smr[t*4+3]=fmaxf(a3+b,0.f);
  }
  { // lrnr1[4,64] = relu(sgl @ leW1_p + leb1_p); K=64
    const float* w = leW1 + p*4096 + t;
    float a0=0.f,a1=0.f,a2=0.f,a3=0.f;
#pragma unroll 4
    for (int k = 0; k < 64; ++k) {
      const float wv = w[k*64];
      const float4 a = F4(&sgl[k*4]);
      a0=fmaf(a.x,wv,a0); a1=fmaf(a.y,wv,a1); a2=fmaf(a.z,wv,a2); a3=fmaf(a.w,wv,a3);
    }
    const float b = leb1[p*64 + t];
    slr[t*4+0]=fmaxf(a0+b,0.f); slr[t*4+1]=fmaxf(a1+b,0.f);
    slr[t*4+2]=fmaxf(a2+b,0.f); slr[t*4+3]=fmaxf(a3+b,0.f);
  }
  __syncthreads();

  { // molr2 -> scomb cols 128+t; lrnr2 -> scomb cols 192+t; K=64 each
    const float* w  = meW2 + p*4096 + t;
    const float* w2 = leW2 + p*4096 + t;
    float a0=0.f,a1=0.f,a2=0.f,a3=0.f;
    float c0=0.f,c1=0.f,c2=0.f,c3=0.f;
#pragma unroll 2
    for (int k = 0; k < 64; ++k) {
      const float wv = w[k*64];
      const float4 a = F4(&smr[k*4]);
      a0=fmaf(a.x,wv,a0); a1=fmaf(a.y,wv,a1); a2=fmaf(a.z,wv,a2); a3=fmaf(a.w,wv,a3);
      const float vv = w2[k*64];
      const float4 b = F4(&slr[k*4]);
      c0=fmaf(b.x,vv,c0); c1=fmaf(b.y,vv,c1); c2=fmaf(b.z,vv,c2); c3=fmaf(b.w,vv,c3);
    }
    const float bm = meb2[p*64 + t], bl_ = leb2[p*64 + t];
    scomb[(128+t)*4+0]=a0+bm; scomb[(128+t)*4+1]=a1+bm;
    scomb[(128+t)*4+2]=a2+bm; scomb[(128+t)*4+3]=a3+bm;
    scomb[(192+t)*4+0]=c0+bl_; scomb[(192+t)*4+1]=c1+bl_;
    scomb[(192+t)*4+2]=c2+bl_; scomb[(192+t)*4+3]=c3+bl_;
  }
  __syncthreads();

  { // fus1[4,128] = relu(scomb @ fW1_p + fb1_p); cols t and t+64, K=256
    const float* w = fW1 + p*32768;
    float a0=0.f,a1=0.f,a2=0.f,a3=0.f;
    float c0=0.f,c1=0.f,c2=0.f,c3=0.f;
#pragma unroll 2
    for (int k = 0; k < 256; ++k) {
      const float4 a = F4(&scomb[k*4]);
      const float w0 = w[k*128 + t];
      const float w1 = w[k*128 + 64 + t];
      a0=fmaf(a.x,w0,a0); a1=fmaf(a.y,w0,a1); a2=fmaf(a.z,w0,a2); a3=fmaf(a.w,w0,a3);
      c0=fmaf(a.x,w1,c0); c1=fmaf(a.y,w1,c1); c2=fmaf(a.z,w1,c2); c3=fmaf(a.w,w1,c3);
    }
    const float b0_ = fb1[p*128 + t], b1_ = fb1[p*128 + 64 + t];
    sf1[t*4+0]=fmaxf(a0+b0_,0.f); sf1[t*4+1]=fmaxf(a1+b0_,0.f);
    sf1[t*4+2]=fmaxf(a2+b0_,0.f); sf1[t*4+3]=fmaxf(a3+b0_,0.f);
    sf1[(t+64)*4+0]=fmaxf(c0+b1_,0.f); sf1[(t+64)*4+1]=fmaxf(c1+b1_,0.f);
    sf1[(t+64)*4+2]=fmaxf(c2+b1_,0.f); sf1[(t+64)*4+3]=fmaxf(c3+b1_,0.f);
  }
  __syncthreads();

  { // fus2[4,64] = sf1 @ fW2_p + fb2_p; K=128
    const float* w = fW2 + p*8192 + t;
    float a0=0.f,a1=0.f,a2=0.f,a3=0.f;
#pragma unroll 4
    for (int k = 0; k < 128; ++k) {
      const float wv = w[k*64];
      const float4 a = F4(&sf1[k*4]);
      a0=fmaf(a.x,wv,a0); a1=fmaf(a.y,wv,a1); a2=fmaf(a.z,wv,a2); a3=fmaf(a.w,wv,a3);
    }
    const float b = fb2[p*64 + t];
    sf2[t*4+0]=a0+b; sf2[t*4+1]=a1+b; sf2[t*4+2]=a2+b; sf2[t*4+3]=a3+b;
  }
  __syncthreads();

  { // h1[4,32] = relu(sf2 @ hW1_p + hb1_p); dot hW2_p; reduce over 32 cols
    float a0=0.f,a1=0.f,a2=0.f,a3=0.f;
    if (t < 32) {
      const float* w = hW1 + p*2048 + t;
#pragma unroll 4
      for (int k = 0; k < 64; ++k) {
        const float wv = w[k*32];
        const float4 a = F4(&sf2[k*4]);
        a0=fmaf(a.x,wv,a0); a1=fmaf(a.y,wv,a1); a2=fmaf(a.z,wv,a2); a3=fmaf(a.w,wv,a3);
      }
      const float hb = hb1[p*32 + t], w2v = hW2[p*32 + t];
      a0 = fmaxf(a0+hb,0.f)*w2v;
      a1 = fmaxf(a1+hb,0.f)*w2v;
      a2 = fmaxf(a2+hb,0.f)*w2v;
      a3 = fmaxf(a3+hb,0.f)*w2v;
    }
#pragma unroll
    for (int o = 1; o < 32; o <<= 1) {
      a0 += __shfl_xor(a0, o);
      a1 += __shfl_xor(a1, o);
      a2 += __shfl_xor(a2, o);
      a3 += __shfl_xor(a3, o);
    }
    if (t == 0) {
      const float hb2v = hb2[p];
      out[p*1024 + b0 + 0] = a0 + hb2v;
      out[p*1024 + b0 + 1] = a1 + hb2v;
      out[p*1024 + b0 + 2] = a2 + hb2v;
      out[p*1024 + b0 + 3] = a3 + hb2v;
    }
  }
}

extern "C" void kernel_launch(void* const* d_in, const int* in_sizes, int n_in,
                              void* d_out, int out_size, void* d_ws, size_t ws_size,
                              hipStream_t stream) {
  const float* x_atoms    = (const float*)d_in[0];
  const float* pos        = (const float*)d_in[1];
  const float* molf       = (const float*)d_in[3];
  const float* emb_W      = (const float*)d_in[4];
  const float* emb_b      = (const float*)d_in[5];
  const float* mp_W1      = (const float*)d_in[6];
  const float* mp_b1      = (const float*)d_in[7];
  const float* mp_W2      = (const float*)d_in[8];
  const float* mp_b2      = (const float*)d_in[9];
  const float* ln_g       = (const float*)d_in[10];
  const float* ln_b       = (const float*)d_in[11];
  const float* attn_in_w  = (const float*)d_in[12];
  const float* attn_in_b  = (const float*)d_in[13];
  const float* attn_out_w = (const float*)d_in[14];
  const float* attn_out_b = (const float*)d_in[15];
  const float* pool_W     = (const float*)d_in[16];
  const float* pool_b     = (const float*)d_in[17];
  const float* mol_gate   = (const float*)d_in[18];
  const float* lrn_gate   = (const float*)d_in[19];
  const float* meW1       = (const float*)d_in[20];
  const float* meb1       = (const float*)d_in[21];
  const float* meW2       = (const float*)d_in[22];
  const float* meb2       = (const float*)d_in[23];
  const float* leW1       = (const float*)d_in[24];
  const float* leb1       = (const float*)d_in[25];
  const float* leW2       = (const float*)d_in[26];
  const float* leb2       = (const float*)d_in[27];
  const float* fW1        = (const float*)d_in[28];
  const float* fb1        = (const float*)d_in[29];
  const float* fW2        = (const float*)d_in[30];
  const float* fb2        = (const float*)d_in[31];
  const float* hW1        = (const float*)d_in[32];
  const float* hb1        = (const float*)d_in[33];
  const float* hW2        = (const float*)d_in[34];
  const float* hb2        = (const float*)d_in[35];
  const int*   ei         = (const int*)d_in[36];

  float* ws      = (float*)d_ws;
  float* x       = ws;                              // NN*128
  float* region  = x + (size_t)NN*128;              // NN*384 floats
  float* P       = region;                          // NN*128 fp32
  unsigned short* Qbf = (unsigned short*)(region + (size_t)NN*128); // NN*128 bf16
  float* dqkv    = region;                          // NN*384 (layer bufs dead)
  float* att     = region + (size_t)NN*384;         // NN*128
  float* csr_rf  = att + (size_t)NN*128;            // NE*4 floats (float4 records)
  float4* csr_rec = (float4*)csr_rf;
  int*   cnt_i   = (int*)(csr_rf + (size_t)NE*4);   // NN
  int*   csr_off = cnt_i + NN;                      // NN+64 (padded)
  int*   cur     = csr_off + NN + 64;               // NN
  float* lrn     = (float*)(cur + NN);              // NB*64
  float* expl    = lrn + NB*64;                     // NB*128
  float* pqbias  = expl + NB*128;                   // 768
  short* bh      = (short*)(pqbias + 768);          // PK_TOTAL shorts
  short* bl      = bh + PK_TOTAL;                   // PK_TOTAL shorts

  hipMemsetAsync(cnt_i, 0, (size_t)NN*sizeof(int), stream);

  prep_kernel<<<(PK_TOTAL + 255)/256, 256, 0, stream>>>(
      mp_W1, mp_W2, attn_in_w, attn_out_w, emb_W, mp_b1, bh, bl, pqbias);
  hist_kernel<<<NE/256, 256, 0, stream>>>(ei, cnt_i);
  scan_kernel<<<1, 1024, 0, stream>>>(cnt_i, csr_off, cur);
  scatter_kernel<<<NE/256, 256, 0, stream>>>(pos, ei, cur, csr_rec);

  // embed via MFMA: x = x_atoms @ emb_W + emb_b
  mfma_gemm_kernel<<<dim3(NN/128, 2), 256, 0, stream>>>(
      x_atoms, 64, 64, bh + EMB_OFF, bl + EMB_OFF, emb_b, x, 128, 128, 0, nullptr);

  for (int l = 0; l < 3; ++l) {
    mfma_gemm_kernel<<<dim3(NN/128, 4), 256, 0, stream>>>(
        x, 128, 128, bh + W1AB_OFF + l*32768, bl + W1AB_OFF + l*32768,
        pqbias + l*256, P, 256, 128, 0, Qbf);
    agg_kernel<<<NN/4, 256, 0, stream>>>(P, Qbf, csr_off, csr_rec,
                                         mp_W1 + (size_t)l*259*128);
    mfma_gemm_ln_kernel<<<NN/64, 256, 0, stream>>>(
        P, 128, bh + W2_OFF + l*16384, bl + W2_OFF + l*16384,
        mp_b2 + l*128, csr_off, ln_g + l*128, ln_b + l*128, x);
  }

  // attention path
  mfma_gemm_kernel<<<dim3(NN/128, 6), 256, 0, stream>>>(
      x, 128, 128, bh + WIN_OFF, bl + WIN_OFF, attn_in_b, dqkv, 384, 384, 0, nullptr);
  attn_kernel<<<NB, 128, 0, stream>>>(dqkv);
  mfma_gemm_kernel<<<dim3(NN/128, 2), 256, 0, stream>>>(
      dqkv + 256, 384, 128, bh + WOUT_OFF, bl + WOUT_OFF, attn_out_b, att, 128, 128, 0, nullptr);
  pool_kernel<<<NB, 128, 0, stream>>>(att, x, pool_W, pool_b, expl, lrn);

  // fused per-property head: 4 molecules/block, 64 threads
  head4_kernel<<<dim3(NB/4, 4), 64, 0, stream>>>(
      molf, lrn, expl, mol_gate, lrn_gate,
      meW1, meb1, meW2, meb2, leW1, leb1, leW2, leb2,
      fW1, fb1, fW2, fb2, hW1, hb1, hW2, hb2, (float*)d_out);
}

// Round 11
// 390.956 us; speedup vs baseline: 1.2086x; 1.1073x over previous
//
#include <hip/hip_runtime.h>

#define NE 524288
#define NN 32768
#define NB 1024

#define F4(p) (*(const float4*)(p))

typedef __bf16 bf16x8 __attribute__((ext_vector_type(8)));
typedef float  f32x4  __attribute__((ext_vector_type(4)));

__device__ __forceinline__ float sigmoidf_(float v) { return 1.f / (1.f + expf(-v)); }

__device__ __forceinline__ void bf16split(float f, short &hi, short &lo) {
  unsigned u = __float_as_uint(f);
  unsigned rh = (u + 0x7FFFu + ((u >> 16) & 1u)) >> 16;
  float fh = __uint_as_float(rh << 16);
  float fl = f - fh;
  unsigned u2 = __float_as_uint(fl);
  unsigned rl = (u2 + 0x7FFFu + ((u2 >> 16) & 1u)) >> 16;
  hi = (short)rh; lo = (short)rl;
}

__device__ __forceinline__ unsigned short f2bf(float f) {
  unsigned u = __float_as_uint(f);
  return (unsigned short)((u + 0x7FFFu + ((u >> 16) & 1u)) >> 16);
}
__device__ __forceinline__ float bf2f(unsigned short h) {
  return __uint_as_float(((unsigned)h) << 16);
}

__device__ __forceinline__ void ld32(float* xr, const float* p) {
#pragma unroll
  for (int i = 0; i < 32; i += 4) {
    float4 v = F4(&p[i]);
    xr[i] = v.x; xr[i+1] = v.y; xr[i+2] = v.z; xr[i+3] = v.w;
  }
}

__device__ __forceinline__ float dot32r(const float* __restrict__ w, const float* xr) {
  float s = 0.f;
#pragma unroll
  for (int i = 0; i < 32; i += 4) {
    float4 ww = F4(&w[i]);
    s = fmaf(xr[i],   ww.x, s);
    s = fmaf(xr[i+1], ww.y, s);
    s = fmaf(xr[i+2], ww.z, s);
    s = fmaf(xr[i+3], ww.w, s);
  }
  return s;
}

// ---------------- CSR build ----------------
__global__ __launch_bounds__(256) void hist_kernel(const int* __restrict__ ei, int* __restrict__ cnt) {
  const int e = blockIdx.x*256 + threadIdx.x;
  atomicAdd(&cnt[ei[NE + e]], 1);
}

__global__ __launch_bounds__(1024) void scan_kernel(
    const int* __restrict__ cnt, int* __restrict__ off, int* __restrict__ cur)
{
  __shared__ int wsum[16];
  const int t = threadIdx.x;
  int local[32];
  const int base = t*32;
  int s = 0;
#pragma unroll
  for (int i = 0; i < 32; ++i) { local[i] = cnt[base+i]; s += local[i]; }
  int pre = s;
  const int lane = t & 63;
#pragma unroll
  for (int o = 1; o < 64; o <<= 1) { int v = __shfl_up(pre, o); if (lane >= o) pre += v; }
  if (lane == 63) wsum[t >> 6] = pre;
  __syncthreads();
  if (t == 0) { int a = 0; for (int w = 0; w < 16; ++w) { int v = wsum[w]; wsum[w] = a; a += v; } }
  __syncthreads();
  int excl = wsum[t >> 6] + pre - s;
#pragma unroll
  for (int i = 0; i < 32; ++i) { off[base+i] = excl; cur[base+i] = excl; excl += local[i]; }
  if (t == 1023) off[NN] = excl;
}

// edge record: {src_as_float, d, 1/(1+d), exp(-d)}
__global__ __launch_bounds__(256) void scatter_kernel(
    const float* __restrict__ pos, const int* __restrict__ ei,
    int* __restrict__ cur, float4* __restrict__ csr_rec)
{
  const int e = blockIdx.x*256 + threadIdx.x;
  const int s = ei[e];
  const int d = ei[NE + e];
  float dx = pos[d*3+0] - pos[s*3+0];
  float dy = pos[d*3+1] - pos[s*3+1];
  float dz = pos[d*3+2] - pos[s*3+2];
  float dist = sqrtf(dx*dx + dy*dy + dz*dz + 1e-12f);
  const int slot = atomicAdd(&cur[d], 1);
  csr_rec[slot] = make_float4(__int_as_float(s), dist, 1.f/(1.f + dist), expf(-dist));
}

// ---------------- weight prep: split-bf16, MFMA-frag-major ----------------
__device__ __forceinline__ void pack_decode(int r, int N, int &k, int &n) {
  const int j = r & 7, lane = (r >> 3) & 63, rest = r >> 9;
  const int NT = N >> 4;
  const int t = rest % NT, kc = rest / NT;
  k = kc*32 + (lane >> 4)*8 + j;
  n = t*16 + (lane & 15);
}

// segment offsets (elements)
#define W1AB_OFF 0        // l*32768, K=128 N=256
#define W2_OFF   98304    // l*16384, K=128 N=128
#define WIN_OFF  147456   // K=128 N=384
#define WOUT_OFF 196608   // K=128 N=128
#define EMB_OFF  212992   // K=64  N=128
#define PK_TOTAL 221184

__global__ __launch_bounds__(256) void prep_kernel(
    const float* __restrict__ mp_W1, const float* __restrict__ mp_W2,
    const float* __restrict__ win, const float* __restrict__ wout,
    const float* __restrict__ emb_W, const float* __restrict__ mp_b1,
    short* __restrict__ bh, short* __restrict__ bl, float* __restrict__ pqbias)
{
  const int i = blockIdx.x*256 + threadIdx.x;
  if (i < 768) { const int l = i >> 8, t = i & 255; pqbias[i] = t < 128 ? mp_b1[l*128 + t] : 0.f; }
  if (i >= PK_TOTAL) return;
  int k, n; float v;
  if (i < W2_OFF) {
    const int l = i / 32768, r = i % 32768;
    pack_decode(r, 256, k, n);
    const float* W = mp_W1 + (size_t)l*259*128;
    v = (n < 128) ? W[k*128 + n] : W[(128+k)*128 + (n-128)];
  } else if (i < WIN_OFF) {
    const int q = i - W2_OFF, l = q / 16384, r = q % 16384;
    pack_decode(r, 128, k, n);
    v = mp_W2[(size_t)l*16384 + k*128 + n];
  } else if (i < WOUT_OFF) {
    pack_decode(i - WIN_OFF, 384, k, n);
    v = win[n*128 + k];
  } else if (i < EMB_OFF) {
    pack_decode(i - WOUT_OFF, 128, k, n);
    v = wout[n*128 + k];
  } else {
    pack_decode(i - EMB_OFF, 128, k, n);   // K=64 segment: k < 64 by construction
    v = emb_W[k*128 + n];
  }
  short h_, lo; bf16split(v, h_, lo);
  bh[i] = h_; bl[i] = lo;
}

// ---------------- generic MFMA GEMM: C[M][·] = op(A[M][K] @ B + bias) ----------------
__global__ __launch_bounds__(256, 2) void mfma_gemm_kernel(
    const float* __restrict__ A, int lda, int K,
    const short* __restrict__ Bh, const short* __restrict__ Bl,
    const float* __restrict__ bias, float* __restrict__ C, int ncols, int ldc,
    int relu, unsigned short* __restrict__ qbf)
{
  const int lane = threadIdx.x & 63, wid = threadIdx.x >> 6;
  const int m0 = blockIdx.x * 128 + wid * 32;
  const int n0 = blockIdx.y * 64;
  const int NT = ncols >> 4;
  const int cl = lane & 15, kg = lane >> 4;
  const int KC = K >> 5;

  f32x4 acc[2][4];
#pragma unroll
  for (int s = 0; s < 2; ++s)
#pragma unroll
    for (int t = 0; t < 4; ++t) acc[s][t] = (f32x4){0.f,0.f,0.f,0.f};

  for (int kc = 0; kc < KC; ++kc) {
    bf16x8 Ah[2], Al[2];
#pragma unroll
    for (int s = 0; s < 2; ++s) {
      const float* ap = &A[(size_t)(m0 + s*16 + cl)*lda + kc*32 + kg*8];
      const float4 f0 = F4(ap), f1 = F4(ap + 4);
      const float fv[8] = {f0.x,f0.y,f0.z,f0.w,f1.x,f1.y,f1.z,f1.w};
      union { short s[8]; bf16x8 b; } uh, ul;
#pragma unroll
      for (int j = 0; j < 8; ++j) bf16split(fv[j], uh.s[j], ul.s[j]);
      Ah[s] = uh.b; Al[s] = ul.b;
    }
    bf16x8 Bfh[4], Bfl[4];
#pragma unroll
    for (int t = 0; t < 4; ++t) {
      const size_t off = (((size_t)(kc*NT + (n0 >> 4) + t))*64 + lane)*8;
      Bfh[t] = *(const bf16x8*)&Bh[off];
      Bfl[t] = *(const bf16x8*)&Bl[off];
    }
#pragma unroll
    for (int s = 0; s < 2; ++s)
#pragma unroll
      for (int t = 0; t < 4; ++t)
        acc[s][t] = __builtin_amdgcn_mfma_f32_16x16x32_bf16(Ah[s], Bfh[t], acc[s][t], 0, 0, 0);
#pragma unroll
    for (int s = 0; s < 2; ++s)
#pragma unroll
      for (int t = 0; t < 4; ++t)
        acc[s][t] = __builtin_amdgcn_mfma_f32_16x16x32_bf16(Ah[s], Bfl[t], acc[s][t], 0, 0, 0);
#pragma unroll
    for (int s = 0; s < 2; ++s)
#pragma unroll
      for (int t = 0; t < 4; ++t)
        acc[s][t] = __builtin_amdgcn_mfma_f32_16x16x32_bf16(Al[s], Bfh[t], acc[s][t], 0, 0, 0);
  }

#pragma unroll
  for (int t = 0; t < 4; ++t) {
    const int col = n0 + t*16 + cl;
    const float bv = bias[col];
#pragma unroll
    for (int s = 0; s < 2; ++s) {
      const int rbase = m0 + s*16 + kg*4;
#pragma unroll
      for (int r = 0; r < 4; ++r) {
        float v = acc[s][t][r] + bv;
        if (relu) v = fmaxf(v, 0.f);
        if (qbf && col >= 128)
          qbf[(size_t)(rbase + r)*128 + (col - 128)] = f2bf(v);
        else
          C[(size_t)(rbase + r)*ldc + col] = v;
      }
    }
  }
}

// ---------------- MFMA GEMM + residual + LN ----------------
__global__ __launch_bounds__(256, 2) void mfma_gemm_ln_kernel(
    const float* __restrict__ A, int lda,
    const short* __restrict__ Bh, const short* __restrict__ Bl,
    const float* __restrict__ b2, const int* __restrict__ csr_off,
    const float* __restrict__ g, const float* __restrict__ bb,
    float* __restrict__ x)
{
  const int lane = threadIdx.x & 63, wid = threadIdx.x >> 6;
  const int m0 = blockIdx.x * 64 + wid * 16;
  const int cl = lane & 15, kg = lane >> 4;

  bf16x8 Ah[4], Al[4];
#pragma unroll
  for (int kc = 0; kc < 4; ++kc) {
    const float* ap = &A[(size_t)(m0 + cl)*lda + kc*32 + kg*8];
    const float4 f0 = F4(ap), f1 = F4(ap + 4);
    const float fv[8] = {f0.x,f0.y,f0.z,f0.w,f1.x,f1.y,f1.z,f1.w};
    union { short s[8]; bf16x8 b; } uh, ul;
#pragma unroll
    for (int j = 0; j < 8; ++j) bf16split(fv[j], uh.s[j], ul.s[j]);
    Ah[kc] = uh.b; Al[kc] = ul.b;
  }

  f32x4 acc[8];
#pragma unroll
  for (int t = 0; t < 8; ++t) acc[t] = (f32x4){0.f,0.f,0.f,0.f};

#pragma unroll
  for (int kc = 0; kc < 4; ++kc) {
    bf16x8 Bfh[8], Bfl[8];
#pragma unroll
    for (int t = 0; t < 8; ++t) {
      const size_t off = (((size_t)(kc*8 + t))*64 + lane)*8;
      Bfh[t] = *(const bf16x8*)&Bh[off];
      Bfl[t] = *(const bf16x8*)&Bl[off];
    }
#pragma unroll
    for (int t = 0; t < 8; ++t)
      acc[t] = __builtin_amdgcn_mfma_f32_16x16x32_bf16(Ah[kc], Bfh[t], acc[t], 0, 0, 0);
#pragma unroll
    for (int t = 0; t < 8; ++t)
      acc[t] = __builtin_amdgcn_mfma_f32_16x16x32_bf16(Ah[kc], Bfl[t], acc[t], 0, 0, 0);
#pragma unroll
    for (int t = 0; t < 8; ++t)
      acc[t] = __builtin_amdgcn_mfma_f32_16x16x32_bf16(Al[kc], Bfh[t], acc[t], 0, 0, 0);
  }

  const int r0 = m0 + kg*4;
  float sflag[4];
#pragma unroll
  for (int r = 0; r < 4; ++r)
    sflag[r] = (csr_off[r0 + r + 1] > csr_off[r0 + r]) ? 1.f : 0.f;

  float ps[4] = {0.f,0.f,0.f,0.f}, pq[4] = {0.f,0.f,0.f,0.f};
  float yv[8][4];
#pragma unroll
  for (int t = 0; t < 8; ++t) {
    const int col = t*16 + cl;
    const float b2v = b2[col];
#pragma unroll
    for (int r = 0; r < 4; ++r) {
      const float y = acc[t][r] + sflag[r]*b2v + x[(size_t)(r0 + r)*128 + col];
      yv[t][r] = y;
      ps[r] += y;
      pq[r] = fmaf(y, y, pq[r]);
    }
  }
#pragma unroll
  for (int o = 1; o < 16; o <<= 1) {
#pragma unroll
    for (int r = 0; r < 4; ++r) { ps[r] += __shfl_xor(ps[r], o); pq[r] += __shfl_xor(pq[r], o); }
  }
#pragma unroll
  for (int r = 0; r < 4; ++r) {
    const float mu = ps[r] * (1.f/128.f);
    const float var = pq[r]*(1.f/128.f) - mu*mu;
    const float rstd = rsqrtf(var + 1e-5f);
#pragma unroll
    for (int t = 0; t < 8; ++t) {
      const int col = t*16 + cl;
      x[(size_t)(r0 + r)*128 + col] = (yv[t][r] - mu)*rstd*g[col] + bb[col];
    }
  }
}

// ---------------- aggregation: P[n] <- mean_e relu(P[n]+Qbf[src]+df@W1c) ----------------
__global__ __launch_bounds__(256, 6) void agg_kernel(
    float* __restrict__ P, const unsigned short* __restrict__ Qbf,
    const int* __restrict__ csr_off, const float4* __restrict__ csr_rec,
    const float* __restrict__ W1)
{
  const int tid = threadIdx.x;
  const int node = blockIdx.x*4 + (tid >> 6);
  const int lane = tid & 63;
  const int c0 = lane*2;
  const int off0 = csr_off[node], off1 = csr_off[node+1];

  const float* __restrict__ w1c = W1 + 256*128;
  const float w00 = w1c[c0],       w01 = w1c[c0+1];
  const float w10 = w1c[128+c0],   w11 = w1c[128+c0+1];
  const float w20 = w1c[256+c0],   w21 = w1c[256+c0+1];
  const float2 p = *(const float2*)&P[(size_t)node*128 + c0];

  float a0 = 0.f, a1 = 0.f;
  int e = off0;
  for (; e + 8 <= off1; e += 8) {
    float4 rc[8];
#pragma unroll
    for (int j = 0; j < 8; ++j) rc[j] = csr_rec[e+j];
    ushort2 qv[8];
#pragma unroll
    for (int j = 0; j < 8; ++j)
      qv[j] = *(const ushort2*)&Qbf[(size_t)__float_as_int(rc[j].x)*128 + c0];
#pragma unroll
    for (int j = 0; j < 8; ++j) {
      float h0 = p.x + bf2f(qv[j].x);
      h0 = fmaf(rc[j].y, w00, h0); h0 = fmaf(rc[j].z, w10, h0); h0 = fmaf(rc[j].w, w20, h0);
      float h1 = p.y + bf2f(qv[j].y);
      h1 = fmaf(rc[j].y, w01, h1); h1 = fmaf(rc[j].z, w11, h1); h1 = fmaf(rc[j].w, w21, h1);
      a0 += fmaxf(h0, 0.f);
      a1 += fmaxf(h1, 0.f);
    }
  }
  for (; e < off1; ++e) {
    const float4 rc = csr_rec[e];
    const ushort2 qv = *(const ushort2*)&Qbf[(size_t)__float_as_int(rc.x)*128 + c0];
    float h0 = p.x + bf2f(qv.x);
    h0 = fmaf(rc.y, w00, h0); h0 = fmaf(rc.z, w10, h0); h0 = fmaf(rc.w, w20, h0);
    float h1 = p.y + bf2f(qv.y);
    h1 = fmaf(rc.y, w01, h1); h1 = fmaf(rc.z, w11, h1); h1 = fmaf(rc.w, w21, h1);
    a0 += fmaxf(h0, 0.f);
    a1 += fmaxf(h1, 0.f);
  }
  const int deg = off1 - off0;
  const float rc_ = deg > 0 ? 1.f/(float)deg : 1.f;
  *(float2*)&P[(size_t)node*128 + c0] = make_float2(a0*rc_, a1*rc_);
}

// ---------------- per-molecule attention on dqkv[n][384]; O -> dv slot ----------------
__global__ __launch_bounds__(128) void attn_kernel(float* __restrict__ dqkv)
{
  __shared__ float sk[32*132];
  __shared__ float sv[32*132];
  const int tid = threadIdx.x;
  const int b = blockIdx.x;

  for (int idx = tid; idx < 1024; idx += 128) {
    const int a = idx >> 5, c4 = idx & 31;
    *(float4*)&sk[a*132 + c4*4] = F4(&dqkv[(size_t)(b*32+a)*384 + 128 + c4*4]);
    *(float4*)&sv[a*132 + c4*4] = F4(&dqkv[(size_t)(b*32+a)*384 + 256 + c4*4]);
  }
  __syncthreads();

  const int h = tid >> 5, qr = tid & 31;
  float qreg[32];
  ld32(qreg, &dqkv[(size_t)(b*32+qr)*384 + h*32]);

  float sc[32];
#pragma unroll
  for (int k = 0; k < 32; ++k)
    sc[k] = dot32r(&sk[k*132 + h*32], qreg) * 0.17677669529663687f;
  float mx = sc[0];
#pragma unroll
  for (int k = 1; k < 32; ++k) mx = fmaxf(mx, sc[k]);
  float se = 0.f;
#pragma unroll
  for (int k = 0; k < 32; ++k) { sc[k] = expf(sc[k] - mx); se += sc[k]; }
  const float inv = 1.f / se;

  __syncthreads();

  float od[32];
#pragma unroll
  for (int i = 0; i < 32; ++i) od[i] = 0.f;
#pragma unroll 4
  for (int k = 0; k < 32; ++k) {
    const float w = sc[k] * inv;
    const float* vr = &sv[k*132 + h*32];
#pragma unroll
    for (int i = 0; i < 32; i += 4) {
      float4 v = F4(&vr[i]);
      od[i]   = fmaf(w, v.x, od[i]);
      od[i+1] = fmaf(w, v.y, od[i+1]);
      od[i+2] = fmaf(w, v.z, od[i+2]);
      od[i+3] = fmaf(w, v.w, od[i+3]);
    }
  }
#pragma unroll
  for (int i = 0; i < 32; i += 4)
    *(float4*)&sk[qr*132 + h*32 + i] = make_float4(od[i], od[i+1], od[i+2], od[i+3]);
  __syncthreads();

  for (int idx = tid; idx < 1024; idx += 128) {
    const int a = idx >> 5, c4 = idx & 31;
    *(float4*)&dqkv[(size_t)(b*32+a)*384 + 256 + c4*4] = F4(&sk[a*132 + c4*4]);
  }
}

// ---------------- per-molecule pooling + proj ----------------
__global__ __launch_bounds__(128) void pool_kernel(
    const float* __restrict__ att, const float* __restrict__ x,
    const float* __restrict__ pW, const float* __restrict__ pb,
    float* __restrict__ expl, float* __restrict__ lrn)
{
  __shared__ float satt[32*132];
  __shared__ float sx[32*132];
  __shared__ float aw_l[32];
  __shared__ float spool[512];
  const int tid = threadIdx.x;
  const int b = blockIdx.x;

  for (int idx = tid; idx < 1024; idx += 128) {
    const int a = idx >> 5, c4 = idx & 31;
    *(float4*)&satt[a*132 + c4*4] = F4(&att[(size_t)(b*32+a)*128 + c4*4]);
    *(float4*)&sx[a*132 + c4*4]   = F4(&x[(size_t)(b*32+a)*128 + c4*4]);
  }
  __syncthreads();

  {
    const int a = tid >> 2, q4 = tid & 3;
    float sp = 0.f;
#pragma unroll
    for (int i = 0; i < 32; ++i)
      sp = fmaf(satt[a*132 + q4*32 + i], sx[a*132 + q4*32 + i], sp);
    sp += __shfl_xor(sp, 1);
    sp += __shfl_xor(sp, 2);
    if (q4 == 0) aw_l[a] = sp;
  }
  __syncthreads();

  {
    float awr[32];
    float mxl = aw_l[0];
#pragma unroll
    for (int a = 1; a < 32; ++a) mxl = fmaxf(mxl, aw_l[a]);
    float se = 0.f;
#pragma unroll
    for (int a = 0; a < 32; ++a) { awr[a] = expf(aw_l[a] - mxl); se += awr[a]; }
    const float inv = 1.f / se;
    const int c = tid;
    float mx = -3.4e38f, sm = 0.f, wm = 0.f, ex = 0.f;
#pragma unroll
    for (int a = 0; a < 32; ++a) {
      const float v = satt[a*132 + c];
      mx = fmaxf(mx, v);
      sm += v;
      wm = fmaf(v, awr[a], wm);
      ex += sx[a*132 + c];
    }
    wm *= inv;
    const float mean = sm * 0.03125f;
    float s2 = 0.f;
#pragma unroll
    for (int a = 0; a < 32; ++a) {
      const float d = satt[a*132 + c] - mean;
      s2 = fmaf(d, d, s2);
    }
    const float stdp = sqrtf(s2 * (1.f/31.f));  // ddof=1
    expl[b*128 + c] = ex * 0.03125f;
    spool[c]       = wm;
    spool[128 + c] = mx;
    spool[256 + c] = mean;
    spool[384 + c] = stdp;
  }
  __syncthreads();

  if (tid < 64) {
    const int k = tid >> 4, qq = tid & 15;
    const float* pk = pW + k*2048;
    float s0 = 0.f, s1 = 0.f, s2 = 0.f, s3 = 0.f;
    for (int h2 = 0; h2 < 128; h2 += 4) {
      s0 = fmaf(spool[k*128 + h2],   pk[h2*16 + qq],     s0);
      s1 = fmaf(spool[k*128 + h2+1], pk[(h2+1)*16 + qq], s1);
      s2 = fmaf(spool[k*128 + h2+2], pk[(h2+2)*16 + qq], s2);
      s3 = fmaf(spool[k*128 + h2+3], pk[(h2+3)*16 + qq], s3);
    }
    lrn[b*64 + tid] = pb[k*16 + qq] + (s0+s1) + (s2+s3);
  }
}

// ---------------- head: 1 molecule x 1 property per block, 64 threads, grid (1024,4) ----------------
// 8-deep batched weight loads per stage (8 outstanding L2 loads -> latency amortized);
// 16 blocks/CU = 4 waves/SIMD from the 4096-block grid.
__global__ __launch_bounds__(64) void head1_kernel(
    const float* __restrict__ molf, const float* __restrict__ lrn,
    const float* __restrict__ expl,
    const float* __restrict__ mol_gate, const float* __restrict__ lrn_gate,
    const float* __restrict__ meW1, const float* __restrict__ meb1,
    const float* __restrict__ meW2, const float* __restrict__ meb2,
    const float* __restrict__ leW1, const float* __restrict__ leb1,
    const float* __restrict__ leW2, const float* __restrict__ leb2,
    const float* __restrict__ fW1, const float* __restrict__ fb1,
    const float* __restrict__ fW2, const float* __restrict__ fb2,
    const float* __restrict__ hW1, const float* __restrict__ hb1,
    const float* __restrict__ hW2, const float* __restrict__ hb2,
    float* __restrict__ out)
{
  const int p = blockIdx.y, b = blockIdx.x, t = threadIdx.x;
  __shared__ float sgm[200];
  __shared__ float sgl[64];
  __shared__ float sA[64];
  __shared__ float sB[64];
  __shared__ float scomb[256];
  __shared__ float sf1[128];
  __shared__ float sf2[64];

  for (int i = t; i < 200; i += 64)
    sgm[i] = molf[(size_t)b*200 + i] * sigmoidf_(mol_gate[p*200 + i]);
  sgl[t] = lrn[(size_t)b*64 + t] * sigmoidf_(lrn_gate[p*64 + t]);
  scomb[t]      = expl[(size_t)b*128 + t];
  scomb[64 + t] = expl[(size_t)b*128 + 64 + t];
  __syncthreads();

  { // sA = relu(sgm @ meW1_p + meb1_p), K=200; 8-deep batches
    const float* w = meW1 + p*12800 + t;
    float a[8] = {0.f,0.f,0.f,0.f,0.f,0.f,0.f,0.f};
    for (int k = 0; k < 200; k += 8) {
      float wv[8], av[8];
#pragma unroll
      for (int j = 0; j < 8; ++j) wv[j] = w[(k+j)*64];
#pragma unroll
      for (int j = 0; j < 8; ++j) av[j] = sgm[k+j];
#pragma unroll
      for (int j = 0; j < 8; ++j) a[j] = fmaf(av[j], wv[j], a[j]);
    }
    sA[t] = fmaxf(((a[0]+a[1])+(a[2]+a[3])) + ((a[4]+a[5])+(a[6]+a[7])) + meb1[p*64 + t], 0.f);
  }
  { // sB = relu(sgl @ leW1_p + leb1_p), K=64
    const float* w = leW1 + p*4096 + t;
    float a[8] = {0.f,0.f,0.f,0.f,0.f,0.f,0.f,0.f};
    for (int k = 0; k < 64; k += 8) {
      float wv[8], av[8];
#pragma unroll
      for (int j = 0; j < 8; ++j) wv[j] = w[(k+j)*64];
#pragma unroll
      for (int j = 0; j < 8; ++j) av[j] = sgl[k+j];
#pragma unroll
      for (int j = 0; j < 8; ++j) a[j] = fmaf(av[j], wv[j], a[j]);
    }
    sB[t] = fmaxf(((a[0]+a[1])+(a[2]+a[3])) + ((a[4]+a[5])+(a[6]+a[7])) + leb1[p*64 + t], 0.f);
  }
  __syncthreads();

  { // scomb[128+t] = sA @ meW2_p + meb2 ; scomb[192+t] = sB @ leW2_p + leb2 ; K=64 each
    const float* w  = meW2 + p*4096 + t;
    const float* w2 = leW2 + p*4096 + t;
    float a[8] = {0.f,0.f,0.f,0.f,0.f,0.f,0.f,0.f};
    float c[8] = {0.f,0.f,0.f,0.f,0.f,0.f,0.f,0.f};
    for (int k = 0; k < 64; k += 8) {
      float wv[8], vv[8], av[8], bv[8];
#pragma unroll
      for (int j = 0; j < 8; ++j) wv[j] = w[(k+j)*64];
#pragma unroll
      for (int j = 0; j < 8; ++j) vv[j] = w2[(k+j)*64];
#pragma unroll
      for (int j = 0; j < 8; ++j) { av[j] = sA[k+j]; bv[j] = sB[k+j]; }
#pragma unroll
      for (int j = 0; j < 8; ++j) {
        a[j] = fmaf(av[j], wv[j], a[j]);
        c[j] = fmaf(bv[j], vv[j], c[j]);
      }
    }
    scomb[128 + t] = ((a[0]+a[1])+(a[2]+a[3])) + ((a[4]+a[5])+(a[6]+a[7])) + meb2[p*64 + t];
    scomb[192 + t] = ((c[0]+c[1])+(c[2]+c[3])) + ((c[4]+c[5])+(c[6]+c[7])) + leb2[p*64 + t];
  }
  __syncthreads();

  { // sf1 = relu(scomb @ fW1_p + fb1_p), K=256, cols t and t+64
    const float* w = fW1 + p*32768;
    float a[8] = {0.f,0.f,0.f,0.f,0.f,0.f,0.f,0.f};
    float c[8] = {0.f,0.f,0.f,0.f,0.f,0.f,0.f,0.f};
    for (int k = 0; k < 256; k += 8) {
      float w0[8], w1[8], av[8];
#pragma unroll
      for (int j = 0; j < 8; ++j) w0[j] = w[(k+j)*128 + t];
#pragma unroll
      for (int j = 0; j < 8; ++j) w1[j] = w[(k+j)*128 + 64 + t];
#pragma unroll
      for (int j = 0; j < 8; ++j) av[j] = scomb[k+j];
#pragma unroll
      for (int j = 0; j < 8; ++j) {
        a[j] = fmaf(av[j], w0[j], a[j]);
        c[j] = fmaf(av[j], w1[j], c[j]);
      }
    }
    sf1[t]      = fmaxf(((a[0]+a[1])+(a[2]+a[3])) + ((a[4]+a[5])+(a[6]+a[7])) + fb1[p*128 + t], 0.f);
    sf1[64 + t] = fmaxf(((c[0]+c[1])+(c[2]+c[3])) + ((c[4]+c[5])+(c[6]+c[7])) + fb1[p*128 + 64 + t], 0.f);
  }
  __syncthreads();

  { // sf2 = sf1 @ fW2_p + fb2_p, K=128
    const float* w = fW2 + p*8192 + t;
    float a[8] = {0.f,0.f,0.f,0.f,0.f,0.f,0.f,0.f};
    for (int k = 0; k < 128; k += 8) {
      float wv[8], av[8];
#pragma unroll
      for (int j = 0; j < 8; ++j) wv[j] = w[(k+j)*64];
#pragma unroll
      for (int j = 0; j < 8; ++j) av[j] = sf1[k+j];
#pragma unroll
      for (int j = 0; j < 8; ++j) a[j] = fmaf(av[j], wv[j], a[j]);
    }
    sf2[t] = ((a[0]+a[1])+(a[2]+a[3])) + ((a[4]+a[5])+(a[6]+a[7])) + fb2[p*64 + t];
  }
  __syncthreads();

  { // h1 = relu(sf2 @ hW1_p + hb1_p)[32]; dot hW2_p; shfl-reduce
    float val = 0.f;
    if (t < 32) {
      const float* w = hW1 + p*2048 + t;
      float a[8] = {0.f,0.f,0.f,0.f,0.f,0.f,0.f,0.f};
      for (int k = 0; k < 64; k += 8) {
        float wv[8], av[8];
#pragma unroll
        for (int j = 0; j < 8; ++j) wv[j] = w[(k+j)*32];
#pragma unroll
        for (int j = 0; j < 8; ++j) av[j] = sf2[k+j];
#pragma unroll
        for (int j = 0; j < 8; ++j) a[j] = fmaf(av[j], wv[j], a[j]);
      }
      const float h1 = ((a[0]+a[1])+(a[2]+a[3])) + ((a[4]+a[5])+(a[6]+a[7])) + hb1[p*32 + t];
      val = fmaxf(h1, 0.f) * hW2[p*32 + t];
    }
#pragma unroll
    for (int o = 1; o < 32; o <<= 1) val += __shfl_xor(val, o);
    if (t == 0) out[p*1024 + b] = val + hb2[p];
  }
}

extern "C" void kernel_launch(void* const* d_in, const int* in_sizes, int n_in,
                              void* d_out, int out_size, void* d_ws, size_t ws_size,
                              hipStream_t stream) {
  const float* x_atoms    = (const float*)d_in[0];
  const float* pos        = (const float*)d_in[1];
  const float* molf       = (const float*)d_in[3];
  const float* emb_W      = (const float*)d_in[4];
  const float* emb_b      = (const float*)d_in[5];
  const float* mp_W1      = (const float*)d_in[6];
  const float* mp_b1      = (const float*)d_in[7];
  const float* mp_W2      = (const float*)d_in[8];
  const float* mp_b2      = (const float*)d_in[9];
  const float* ln_g       = (const float*)d_in[10];
  const float* ln_b       = (const float*)d_in[11];
  const float* attn_in_w  = (const float*)d_in[12];
  const float* attn_in_b  = (const float*)d_in[13];
  const float* attn_out_w = (const float*)d_in[14];
  const float* attn_out_b = (const float*)d_in[15];
  const float* pool_W     = (const float*)d_in[16];
  const float* pool_b     = (const float*)d_in[17];
  const float* mol_gate   = (const float*)d_in[18];
  const float* lrn_gate   = (const float*)d_in[19];
  const float* meW1       = (const float*)d_in[20];
  const float* meb1       = (const float*)d_in[21];
  const float* meW2       = (const float*)d_in[22];
  const float* meb2       = (const float*)d_in[23];
  const float* leW1       = (const float*)d_in[24];
  const float* leb1       = (const float*)d_in[25];
  const float* leW2       = (const float*)d_in[26];
  const float* leb2       = (const float*)d_in[27];
  const float* fW1        = (const float*)d_in[28];
  const float* fb1        = (const float*)d_in[29];
  const float* fW2        = (const float*)d_in[30];
  const float* fb2        = (const float*)d_in[31];
  const float* hW1        = (const float*)d_in[32];
  const float* hb1        = (const float*)d_in[33];
  const float* hW2        = (const float*)d_in[34];
  const float* hb2        = (const float*)d_in[35];
  const int*   ei         = (const int*)d_in[36];

  float* ws      = (float*)d_ws;
  float* x       = ws;                              // NN*128
  float* region  = x + (size_t)NN*128;              // NN*384 floats
  float* P       = region;                          // NN*128 fp32
  unsigned short* Qbf = (unsigned short*)(region + (size_t)NN*128); // NN*128 bf16
  float* dqkv    = region;                          // NN*384 (layer bufs dead)
  float* att     = region + (size_t)NN*384;         // NN*128
  float* csr_rf  = att + (size_t)NN*128;            // NE*4 floats (float4 records)
  float4* csr_rec = (float4*)csr_rf;
  int*   cnt_i   = (int*)(csr_rf + (size_t)NE*4);   // NN
  int*   csr_off = cnt_i + NN;                      // NN+64 (padded)
  int*   cur     = csr_off + NN + 64;               // NN
  float* lrn     = (float*)(cur + NN);              // NB*64
  float* expl    = lrn + NB*64;                     // NB*128
  float* pqbias  = expl + NB*128;                   // 768
  short* bh      = (short*)(pqbias + 768);          // PK_TOTAL shorts
  short* bl      = bh + PK_TOTAL;                   // PK_TOTAL shorts

  hipMemsetAsync(cnt_i, 0, (size_t)NN*sizeof(int), stream);

  prep_kernel<<<(PK_TOTAL + 255)/256, 256, 0, stream>>>(
      mp_W1, mp_W2, attn_in_w, attn_out_w, emb_W, mp_b1, bh, bl, pqbias);
  hist_kernel<<<NE/256, 256, 0, stream>>>(ei, cnt_i);
  scan_kernel<<<1, 1024, 0, stream>>>(cnt_i, csr_off, cur);
  scatter_kernel<<<NE/256, 256, 0, stream>>>(pos, ei, cur, csr_rec);

  // embed via MFMA: x = x_atoms @ emb_W + emb_b
  mfma_gemm_kernel<<<dim3(NN/128, 2), 256, 0, stream>>>(
      x_atoms, 64, 64, bh + EMB_OFF, bl + EMB_OFF, emb_b, x, 128, 128, 0, nullptr);

  for (int l = 0; l < 3; ++l) {
    mfma_gemm_kernel<<<dim3(NN/128, 4), 256, 0, stream>>>(
        x, 128, 128, bh + W1AB_OFF + l*32768, bl + W1AB_OFF + l*32768,
        pqbias + l*256, P, 256, 128, 0, Qbf);
    agg_kernel<<<NN/4, 256, 0, stream>>>(P, Qbf, csr_off, csr_rec,
                                         mp_W1 + (size_t)l*259*128);
    mfma_gemm_ln_kernel<<<NN/64, 256, 0, stream>>>(
        P, 128, bh + W2_OFF + l*16384, bl + W2_OFF + l*16384,
        mp_b2 + l*128, csr_off, ln_g + l*128, ln_b + l*128, x);
  }

  // attention path
  mfma_gemm_kernel<<<dim3(NN/128, 6), 256, 0, stream>>>(
      x, 128, 128, bh + WIN_OFF, bl + WIN_OFF, attn_in_b, dqkv, 384, 384, 0, nullptr);
  attn_kernel<<<NB, 128, 0, stream>>>(dqkv);
  mfma_gemm_kernel<<<dim3(NN/128, 2), 256, 0, stream>>>(
      dqkv + 256, 384, 128, bh + WOUT_OFF, bl + WOUT_OFF, attn_out_b, att, 128, 128, 0, nullptr);
  pool_kernel<<<NB, 128, 0, stream>>>(att, x, pool_W, pool_b, expl, lrn);

  // per-(molecule, property) head: 1 mol/block, 8-deep pipelined loads
  head1_kernel<<<dim3(NB, 4), 64, 0, stream>>>(
      molf, lrn, expl, mol_gate, lrn_gate,
      meW1, meb1, meW2, meb2, leW1, leb1, leW2, leb2,
      fW1, fb1, fW2, fb2, hW1, hb1, hW2, hb2, (float*)d_out);
}

// Round 12
// 389.954 us; speedup vs baseline: 1.2117x; 1.0026x over previous
//
#include <hip/hip_runtime.h>

#define NE 524288
#define NN 32768
#define NB 1024

#define F4(p) (*(const float4*)(p))

typedef __bf16 bf16x8 __attribute__((ext_vector_type(8)));
typedef float  f32x4  __attribute__((ext_vector_type(4)));

__device__ __forceinline__ float sigmoidf_(float v) { return 1.f / (1.f + expf(-v)); }

__device__ __forceinline__ void bf16split(float f, short &hi, short &lo) {
  unsigned u = __float_as_uint(f);
  unsigned rh = (u + 0x7FFFu + ((u >> 16) & 1u)) >> 16;
  float fh = __uint_as_float(rh << 16);
  float fl = f - fh;
  unsigned u2 = __float_as_uint(fl);
  unsigned rl = (u2 + 0x7FFFu + ((u2 >> 16) & 1u)) >> 16;
  hi = (short)rh; lo = (short)rl;
}

__device__ __forceinline__ unsigned short f2bf(float f) {
  unsigned u = __float_as_uint(f);
  return (unsigned short)((u + 0x7FFFu + ((u >> 16) & 1u)) >> 16);
}
__device__ __forceinline__ float bf2f(unsigned short h) {
  return __uint_as_float(((unsigned)h) << 16);
}

__device__ __forceinline__ void ld32(float* xr, const float* p) {
#pragma unroll
  for (int i = 0; i < 32; i += 4) {
    float4 v = F4(&p[i]);
    xr[i] = v.x; xr[i+1] = v.y; xr[i+2] = v.z; xr[i+3] = v.w;
  }
}

__device__ __forceinline__ float dot32r(const float* __restrict__ w, const float* xr) {
  float s = 0.f;
#pragma unroll
  for (int i = 0; i < 32; i += 4) {
    float4 ww = F4(&w[i]);
    s = fmaf(xr[i],   ww.x, s);
    s = fmaf(xr[i+1], ww.y, s);
    s = fmaf(xr[i+2], ww.z, s);
    s = fmaf(xr[i+3], ww.w, s);
  }
  return s;
}

// ---------------- CSR build ----------------
__global__ __launch_bounds__(256) void hist_kernel(const int* __restrict__ ei, int* __restrict__ cnt) {
  const int e = blockIdx.x*256 + threadIdx.x;
  atomicAdd(&cnt[ei[NE + e]], 1);
}

__global__ __launch_bounds__(1024) void scan_kernel(
    const int* __restrict__ cnt, int* __restrict__ off, int* __restrict__ cur)
{
  __shared__ int wsum[16];
  const int t = threadIdx.x;
  int local[32];
  const int base = t*32;
  int s = 0;
#pragma unroll
  for (int i = 0; i < 32; ++i) { local[i] = cnt[base+i]; s += local[i]; }
  int pre = s;
  const int lane = t & 63;
#pragma unroll
  for (int o = 1; o < 64; o <<= 1) { int v = __shfl_up(pre, o); if (lane >= o) pre += v; }
  if (lane == 63) wsum[t >> 6] = pre;
  __syncthreads();
  if (t == 0) { int a = 0; for (int w = 0; w < 16; ++w) { int v = wsum[w]; wsum[w] = a; a += v; } }
  __syncthreads();
  int excl = wsum[t >> 6] + pre - s;
#pragma unroll
  for (int i = 0; i < 32; ++i) { off[base+i] = excl; cur[base+i] = excl; excl += local[i]; }
  if (t == 1023) off[NN] = excl;
}

// edge record: {src_as_float, d, 1/(1+d), exp(-d)}
__global__ __launch_bounds__(256) void scatter_kernel(
    const float* __restrict__ pos, const int* __restrict__ ei,
    int* __restrict__ cur, float4* __restrict__ csr_rec)
{
  const int e = blockIdx.x*256 + threadIdx.x;
  const int s = ei[e];
  const int d = ei[NE + e];
  float dx = pos[d*3+0] - pos[s*3+0];
  float dy = pos[d*3+1] - pos[s*3+1];
  float dz = pos[d*3+2] - pos[s*3+2];
  float dist = sqrtf(dx*dx + dy*dy + dz*dz + 1e-12f);
  const int slot = atomicAdd(&cur[d], 1);
  csr_rec[slot] = make_float4(__int_as_float(s), dist, 1.f/(1.f + dist), expf(-dist));
}

// ---------------- weight prep: split-bf16, MFMA-frag-major ----------------
__device__ __forceinline__ void pack_decode(int r, int N, int &k, int &n) {
  const int j = r & 7, lane = (r >> 3) & 63, rest = r >> 9;
  const int NT = N >> 4;
  const int t = rest % NT, kc = rest / NT;
  k = kc*32 + (lane >> 4)*8 + j;
  n = t*16 + (lane & 15);
}

// segment offsets (elements)
#define W1AB_OFF 0        // l*32768, K=128 N=256
#define W2_OFF   98304    // l*16384, K=128 N=128
#define WIN_OFF  147456   // K=128 N=384
#define WOUT_OFF 196608   // K=128 N=128
#define EMB_OFF  212992   // K=64  N=128
#define PK_TOTAL 221184

__global__ __launch_bounds__(256) void prep_kernel(
    const float* __restrict__ mp_W1, const float* __restrict__ mp_W2,
    const float* __restrict__ win, const float* __restrict__ wout,
    const float* __restrict__ emb_W, const float* __restrict__ mp_b1,
    short* __restrict__ bh, short* __restrict__ bl, float* __restrict__ pqbias)
{
  const int i = blockIdx.x*256 + threadIdx.x;
  if (i < 768) { const int l = i >> 8, t = i & 255; pqbias[i] = t < 128 ? mp_b1[l*128 + t] : 0.f; }
  if (i >= PK_TOTAL) return;
  int k, n; float v;
  if (i < W2_OFF) {
    const int l = i / 32768, r = i % 32768;
    pack_decode(r, 256, k, n);
    const float* W = mp_W1 + (size_t)l*259*128;
    v = (n < 128) ? W[k*128 + n] : W[(128+k)*128 + (n-128)];
  } else if (i < WIN_OFF) {
    const int q = i - W2_OFF, l = q / 16384, r = q % 16384;
    pack_decode(r, 128, k, n);
    v = mp_W2[(size_t)l*16384 + k*128 + n];
  } else if (i < WOUT_OFF) {
    pack_decode(i - WIN_OFF, 384, k, n);
    v = win[n*128 + k];
  } else if (i < EMB_OFF) {
    pack_decode(i - WOUT_OFF, 128, k, n);
    v = wout[n*128 + k];
  } else {
    pack_decode(i - EMB_OFF, 128, k, n);   // K=64 segment: k < 64 by construction
    v = emb_W[k*128 + n];
  }
  short h_, lo; bf16split(v, h_, lo);
  bh[i] = h_; bl[i] = lo;
}

// ---------------- generic MFMA GEMM: C[M][·] = op(A[M][K] @ B + bias) ----------------
__global__ __launch_bounds__(256, 2) void mfma_gemm_kernel(
    const float* __restrict__ A, int lda, int K,
    const short* __restrict__ Bh, const short* __restrict__ Bl,
    const float* __restrict__ bias, float* __restrict__ C, int ncols, int ldc,
    int relu, unsigned short* __restrict__ qbf)
{
  const int lane = threadIdx.x & 63, wid = threadIdx.x >> 6;
  const int m0 = blockIdx.x * 128 + wid * 32;
  const int n0 = blockIdx.y * 64;
  const int NT = ncols >> 4;
  const int cl = lane & 15, kg = lane >> 4;
  const int KC = K >> 5;

  f32x4 acc[2][4];
#pragma unroll
  for (int s = 0; s < 2; ++s)
#pragma unroll
    for (int t = 0; t < 4; ++t) acc[s][t] = (f32x4){0.f,0.f,0.f,0.f};

  for (int kc = 0; kc < KC; ++kc) {
    bf16x8 Ah[2], Al[2];
#pragma unroll
    for (int s = 0; s < 2; ++s) {
      const float* ap = &A[(size_t)(m0 + s*16 + cl)*lda + kc*32 + kg*8];
      const float4 f0 = F4(ap), f1 = F4(ap + 4);
      const float fv[8] = {f0.x,f0.y,f0.z,f0.w,f1.x,f1.y,f1.z,f1.w};
      union { short s[8]; bf16x8 b; } uh, ul;
#pragma unroll
      for (int j = 0; j < 8; ++j) bf16split(fv[j], uh.s[j], ul.s[j]);
      Ah[s] = uh.b; Al[s] = ul.b;
    }
    bf16x8 Bfh[4], Bfl[4];
#pragma unroll
    for (int t = 0; t < 4; ++t) {
      const size_t off = (((size_t)(kc*NT + (n0 >> 4) + t))*64 + lane)*8;
      Bfh[t] = *(const bf16x8*)&Bh[off];
      Bfl[t] = *(const bf16x8*)&Bl[off];
    }
#pragma unroll
    for (int s = 0; s < 2; ++s)
#pragma unroll
      for (int t = 0; t < 4; ++t)
        acc[s][t] = __builtin_amdgcn_mfma_f32_16x16x32_bf16(Ah[s], Bfh[t], acc[s][t], 0, 0, 0);
#pragma unroll
    for (int s = 0; s < 2; ++s)
#pragma unroll
      for (int t = 0; t < 4; ++t)
        acc[s][t] = __builtin_amdgcn_mfma_f32_16x16x32_bf16(Ah[s], Bfl[t], acc[s][t], 0, 0, 0);
#pragma unroll
    for (int s = 0; s < 2; ++s)
#pragma unroll
      for (int t = 0; t < 4; ++t)
        acc[s][t] = __builtin_amdgcn_mfma_f32_16x16x32_bf16(Al[s], Bfh[t], acc[s][t], 0, 0, 0);
  }

#pragma unroll
  for (int t = 0; t < 4; ++t) {
    const int col = n0 + t*16 + cl;
    const float bv = bias[col];
#pragma unroll
    for (int s = 0; s < 2; ++s) {
      const int rbase = m0 + s*16 + kg*4;
#pragma unroll
      for (int r = 0; r < 4; ++r) {
        float v = acc[s][t][r] + bv;
        if (relu) v = fmaxf(v, 0.f);
        if (qbf && col >= 128)
          qbf[(size_t)(rbase + r)*128 + (col - 128)] = f2bf(v);
        else
          C[(size_t)(rbase + r)*ldc + col] = v;
      }
    }
  }
}

// ---------------- MFMA GEMM + residual + LN ----------------
__global__ __launch_bounds__(256, 2) void mfma_gemm_ln_kernel(
    const float* __restrict__ A, int lda,
    const short* __restrict__ Bh, const short* __restrict__ Bl,
    const float* __restrict__ b2, const int* __restrict__ csr_off,
    const float* __restrict__ g, const float* __restrict__ bb,
    float* __restrict__ x)
{
  const int lane = threadIdx.x & 63, wid = threadIdx.x >> 6;
  const int m0 = blockIdx.x * 64 + wid * 16;
  const int cl = lane & 15, kg = lane >> 4;

  bf16x8 Ah[4], Al[4];
#pragma unroll
  for (int kc = 0; kc < 4; ++kc) {
    const float* ap = &A[(size_t)(m0 + cl)*lda + kc*32 + kg*8];
    const float4 f0 = F4(ap), f1 = F4(ap + 4);
    const float fv[8] = {f0.x,f0.y,f0.z,f0.w,f1.x,f1.y,f1.z,f1.w};
    union { short s[8]; bf16x8 b; } uh, ul;
#pragma unroll
    for (int j = 0; j < 8; ++j) bf16split(fv[j], uh.s[j], ul.s[j]);
    Ah[kc] = uh.b; Al[kc] = ul.b;
  }

  f32x4 acc[8];
#pragma unroll
  for (int t = 0; t < 8; ++t) acc[t] = (f32x4){0.f,0.f,0.f,0.f};

#pragma unroll
  for (int kc = 0; kc < 4; ++kc) {
    bf16x8 Bfh[8], Bfl[8];
#pragma unroll
    for (int t = 0; t < 8; ++t) {
      const size_t off = (((size_t)(kc*8 + t))*64 + lane)*8;
      Bfh[t] = *(const bf16x8*)&Bh[off];
      Bfl[t] = *(const bf16x8*)&Bl[off];
    }
#pragma unroll
    for (int t = 0; t < 8; ++t)
      acc[t] = __builtin_amdgcn_mfma_f32_16x16x32_bf16(Ah[kc], Bfh[t], acc[t], 0, 0, 0);
#pragma unroll
    for (int t = 0; t < 8; ++t)
      acc[t] = __builtin_amdgcn_mfma_f32_16x16x32_bf16(Ah[kc], Bfl[t], acc[t], 0, 0, 0);
#pragma unroll
    for (int t = 0; t < 8; ++t)
      acc[t] = __builtin_amdgcn_mfma_f32_16x16x32_bf16(Al[kc], Bfh[t], acc[t], 0, 0, 0);
  }

  const int r0 = m0 + kg*4;
  float sflag[4];
#pragma unroll
  for (int r = 0; r < 4; ++r)
    sflag[r] = (csr_off[r0 + r + 1] > csr_off[r0 + r]) ? 1.f : 0.f;

  float ps[4] = {0.f,0.f,0.f,0.f}, pq[4] = {0.f,0.f,0.f,0.f};
  float yv[8][4];
#pragma unroll
  for (int t = 0; t < 8; ++t) {
    const int col = t*16 + cl;
    const float b2v = b2[col];
#pragma unroll
    for (int r = 0; r < 4; ++r) {
      const float y = acc[t][r] + sflag[r]*b2v + x[(size_t)(r0 + r)*128 + col];
      yv[t][r] = y;
      ps[r] += y;
      pq[r] = fmaf(y, y, pq[r]);
    }
  }
#pragma unroll
  for (int o = 1; o < 16; o <<= 1) {
#pragma unroll
    for (int r = 0; r < 4; ++r) { ps[r] += __shfl_xor(ps[r], o); pq[r] += __shfl_xor(pq[r], o); }
  }
#pragma unroll
  for (int r = 0; r < 4; ++r) {
    const float mu = ps[r] * (1.f/128.f);
    const float var = pq[r]*(1.f/128.f) - mu*mu;
    const float rstd = rsqrtf(var + 1e-5f);
#pragma unroll
    for (int t = 0; t < 8; ++t) {
      const int col = t*16 + cl;
      x[(size_t)(r0 + r)*128 + col] = (yv[t][r] - mu)*rstd*g[col] + bb[col];
    }
  }
}

// ---------------- aggregation: P[n] <- mean_e relu(P[n]+Qbf[src]+df@W1c) ----------------
__global__ __launch_bounds__(256, 6) void agg_kernel(
    float* __restrict__ P, const unsigned short* __restrict__ Qbf,
    const int* __restrict__ csr_off, const float4* __restrict__ csr_rec,
    const float* __restrict__ W1)
{
  const int tid = threadIdx.x;
  const int node = blockIdx.x*4 + (tid >> 6);
  const int lane = tid & 63;
  const int c0 = lane*2;
  const int off0 = csr_off[node], off1 = csr_off[node+1];

  const float* __restrict__ w1c = W1 + 256*128;
  const float w00 = w1c[c0],       w01 = w1c[c0+1];
  const float w10 = w1c[128+c0],   w11 = w1c[128+c0+1];
  const float w20 = w1c[256+c0],   w21 = w1c[256+c0+1];
  const float2 p = *(const float2*)&P[(size_t)node*128 + c0];

  float a0 = 0.f, a1 = 0.f;
  int e = off0;
  for (; e + 8 <= off1; e += 8) {
    float4 rc[8];
#pragma unroll
    for (int j = 0; j < 8; ++j) rc[j] = csr_rec[e+j];
    ushort2 qv[8];
#pragma unroll
    for (int j = 0; j < 8; ++j)
      qv[j] = *(const ushort2*)&Qbf[(size_t)__float_as_int(rc[j].x)*128 + c0];
#pragma unroll
    for (int j = 0; j < 8; ++j) {
      float h0 = p.x + bf2f(qv[j].x);
      h0 = fmaf(rc[j].y, w00, h0); h0 = fmaf(rc[j].z, w10, h0); h0 = fmaf(rc[j].w, w20, h0);
      float h1 = p.y + bf2f(qv[j].y);
      h1 = fmaf(rc[j].y, w01, h1); h1 = fmaf(rc[j].z, w11, h1); h1 = fmaf(rc[j].w, w21, h1);
      a0 += fmaxf(h0, 0.f);
      a1 += fmaxf(h1, 0.f);
    }
  }
  for (; e < off1; ++e) {
    const float4 rc = csr_rec[e];
    const ushort2 qv = *(const ushort2*)&Qbf[(size_t)__float_as_int(rc.x)*128 + c0];
    float h0 = p.x + bf2f(qv.x);
    h0 = fmaf(rc.y, w00, h0); h0 = fmaf(rc.z, w10, h0); h0 = fmaf(rc.w, w20, h0);
    float h1 = p.y + bf2f(qv.y);
    h1 = fmaf(rc.y, w01, h1); h1 = fmaf(rc.z, w11, h1); h1 = fmaf(rc.w, w21, h1);
    a0 += fmaxf(h0, 0.f);
    a1 += fmaxf(h1, 0.f);
  }
  const int deg = off1 - off0;
  const float rc_ = deg > 0 ? 1.f/(float)deg : 1.f;
  *(float2*)&P[(size_t)node*128 + c0] = make_float2(a0*rc_, a1*rc_);
}

// ---------------- per-molecule attention on dqkv[n][384]; O -> dv slot ----------------
__global__ __launch_bounds__(128) void attn_kernel(float* __restrict__ dqkv)
{
  __shared__ float sk[32*132];
  __shared__ float sv[32*132];
  const int tid = threadIdx.x;
  const int b = blockIdx.x;

  for (int idx = tid; idx < 1024; idx += 128) {
    const int a = idx >> 5, c4 = idx & 31;
    *(float4*)&sk[a*132 + c4*4] = F4(&dqkv[(size_t)(b*32+a)*384 + 128 + c4*4]);
    *(float4*)&sv[a*132 + c4*4] = F4(&dqkv[(size_t)(b*32+a)*384 + 256 + c4*4]);
  }
  __syncthreads();

  const int h = tid >> 5, qr = tid & 31;
  float qreg[32];
  ld32(qreg, &dqkv[(size_t)(b*32+qr)*384 + h*32]);

  float sc[32];
#pragma unroll
  for (int k = 0; k < 32; ++k)
    sc[k] = dot32r(&sk[k*132 + h*32], qreg) * 0.17677669529663687f;
  float mx = sc[0];
#pragma unroll
  for (int k = 1; k < 32; ++k) mx = fmaxf(mx, sc[k]);
  float se = 0.f;
#pragma unroll
  for (int k = 0; k < 32; ++k) { sc[k] = expf(sc[k] - mx); se += sc[k]; }
  const float inv = 1.f / se;

  __syncthreads();

  float od[32];
#pragma unroll
  for (int i = 0; i < 32; ++i) od[i] = 0.f;
#pragma unroll 4
  for (int k = 0; k < 32; ++k) {
    const float w = sc[k] * inv;
    const float* vr = &sv[k*132 + h*32];
#pragma unroll
    for (int i = 0; i < 32; i += 4) {
      float4 v = F4(&vr[i]);
      od[i]   = fmaf(w, v.x, od[i]);
      od[i+1] = fmaf(w, v.y, od[i+1]);
      od[i+2] = fmaf(w, v.z, od[i+2]);
      od[i+3] = fmaf(w, v.w, od[i+3]);
    }
  }
#pragma unroll
  for (int i = 0; i < 32; i += 4)
    *(float4*)&sk[qr*132 + h*32 + i] = make_float4(od[i], od[i+1], od[i+2], od[i+3]);
  __syncthreads();

  for (int idx = tid; idx < 1024; idx += 128) {
    const int a = idx >> 5, c4 = idx & 31;
    *(float4*)&dqkv[(size_t)(b*32+a)*384 + 256 + c4*4] = F4(&sk[a*132 + c4*4]);
  }
}

// ---------------- fused pooling + proj + per-property head ----------------
// block = 256 threads (4 waves) = 1 molecule; head phase: wave = property.
// Head LDS workspaces alias satt (dead after pooling). 8-deep batched weight loads.
__global__ __launch_bounds__(256) void pool_head_kernel(
    const float* __restrict__ att, const float* __restrict__ x,
    const float* __restrict__ pW, const float* __restrict__ pb,
    const float* __restrict__ molf,
    const float* __restrict__ mol_gate, const float* __restrict__ lrn_gate,
    const float* __restrict__ meW1, const float* __restrict__ meb1,
    const float* __restrict__ meW2, const float* __restrict__ meb2,
    const float* __restrict__ leW1, const float* __restrict__ leb1,
    const float* __restrict__ leW2, const float* __restrict__ leb2,
    const float* __restrict__ fW1, const float* __restrict__ fb1,
    const float* __restrict__ fW2, const float* __restrict__ fb2,
    const float* __restrict__ hW1, const float* __restrict__ hb1,
    const float* __restrict__ hW2, const float* __restrict__ hb2,
    float* __restrict__ out)
{
  const int b = blockIdx.x, tid = threadIdx.x;
  __shared__ float satt[4224];   // [32][132]; aliased by head workspaces later
  __shared__ float sx[4224];
  __shared__ float aw_l[32];
  __shared__ float spool[512];
  __shared__ float slrn[64];
  __shared__ float sexpl[128];

  for (int idx = tid; idx < 1024; idx += 256) {
    const int a = idx >> 5, c4 = idx & 31;
    *(float4*)&satt[a*132 + c4*4] = F4(&att[(size_t)(b*32+a)*128 + c4*4]);
    *(float4*)&sx[a*132 + c4*4]   = F4(&x[(size_t)(b*32+a)*128 + c4*4]);
  }
  __syncthreads();

  { // aw logits: 8 threads/row
    const int a = tid >> 3, q8 = tid & 7;
    float sp = 0.f;
#pragma unroll
    for (int i = 0; i < 16; ++i)
      sp = fmaf(satt[a*132 + q8*16 + i], sx[a*132 + q8*16 + i], sp);
    sp += __shfl_xor(sp, 1);
    sp += __shfl_xor(sp, 2);
    sp += __shfl_xor(sp, 4);
    if (q8 == 0) aw_l[a] = sp;
  }
  __syncthreads();

  if (tid < 128) { // pooling per column
    float awr[32];
    float mxl = aw_l[0];
#pragma unroll
    for (int a = 1; a < 32; ++a) mxl = fmaxf(mxl, aw_l[a]);
    float se = 0.f;
#pragma unroll
    for (int a = 0; a < 32; ++a) { awr[a] = expf(aw_l[a] - mxl); se += awr[a]; }
    const float inv = 1.f / se;
    const int c = tid;
    float mx = -3.4e38f, sm = 0.f, wm = 0.f, ex = 0.f;
#pragma unroll
    for (int a = 0; a < 32; ++a) {
      const float v = satt[a*132 + c];
      mx = fmaxf(mx, v);
      sm += v;
      wm = fmaf(v, awr[a], wm);
      ex += sx[a*132 + c];
    }
    wm *= inv;
    const float mean = sm * 0.03125f;
    float s2 = 0.f;
#pragma unroll
    for (int a = 0; a < 32; ++a) {
      const float d = satt[a*132 + c] - mean;
      s2 = fmaf(d, d, s2);
    }
    const float stdp = sqrtf(s2 * (1.f/31.f));  // ddof=1
    sexpl[c]       = ex * 0.03125f;
    spool[c]       = wm;
    spool[128 + c] = mx;
    spool[256 + c] = mean;
    spool[384 + c] = stdp;
  }
  __syncthreads();  // satt fully read -> reusable as head workspace

  // proj (tid<64) runs while other threads stage sgm into the satt alias.
  float* hb_ = satt;  // per-p workspace: 840 floats each
  if (tid < 64) {
    const int k = tid >> 4, qq = tid & 15;
    const float* pk = pW + k*2048;
    float s0 = 0.f, s1 = 0.f, s2 = 0.f, s3 = 0.f;
    for (int h2 = 0; h2 < 128; h2 += 4) {
      s0 = fmaf(spool[k*128 + h2],   pk[h2*16 + qq],     s0);
      s1 = fmaf(spool[k*128 + h2+1], pk[(h2+1)*16 + qq], s1);
      s2 = fmaf(spool[k*128 + h2+2], pk[(h2+2)*16 + qq], s2);
      s3 = fmaf(spool[k*128 + h2+3], pk[(h2+3)*16 + qq], s3);
    }
    slrn[tid] = pb[k*16 + qq] + (s0+s1) + (s2+s3);
  } else {
    for (int idx = tid - 64; idx < 800; idx += 192) {
      const int p = idx / 200, k = idx - p*200;
      hb_[p*840 + k] = molf[(size_t)b*200 + k] * sigmoidf_(mol_gate[p*200 + k]);
    }
  }
  __syncthreads();

  const int p = tid >> 6, t = tid & 63;
  float* __restrict__ sgm = hb_ + p*840;       // 200
  float* __restrict__ sgl = sgm + 200;         // 64
  float* __restrict__ sAp = sgm + 264;         // 64
  float* __restrict__ sBp = sgm + 328;         // 64
  float* __restrict__ scb = sgm + 392;         // 256
  float* __restrict__ sf1 = sgm + 648;         // 128
  float* __restrict__ sf2 = sgm + 776;         // 64

  sgl[t]      = slrn[t] * sigmoidf_(lrn_gate[p*64 + t]);
  scb[t]      = sexpl[t];
  scb[64 + t] = sexpl[64 + t];
  __syncthreads();

  { // sA = relu(sgm @ meW1_p + meb1_p), K=200
    const float* w = meW1 + p*12800 + t;
    float a[8] = {0.f,0.f,0.f,0.f,0.f,0.f,0.f,0.f};
    for (int k = 0; k < 200; k += 8) {
      float wv[8], av[8];
#pragma unroll
      for (int j = 0; j < 8; ++j) wv[j] = w[(k+j)*64];
#pragma unroll
      for (int j = 0; j < 8; ++j) av[j] = sgm[k+j];
#pragma unroll
      for (int j = 0; j < 8; ++j) a[j] = fmaf(av[j], wv[j], a[j]);
    }
    sAp[t] = fmaxf(((a[0]+a[1])+(a[2]+a[3])) + ((a[4]+a[5])+(a[6]+a[7])) + meb1[p*64 + t], 0.f);
  }
  { // sB = relu(sgl @ leW1_p + leb1_p), K=64
    const float* w = leW1 + p*4096 + t;
    float a[8] = {0.f,0.f,0.f,0.f,0.f,0.f,0.f,0.f};
    for (int k = 0; k < 64; k += 8) {
      float wv[8], av[8];
#pragma unroll
      for (int j = 0; j < 8; ++j) wv[j] = w[(k+j)*64];
#pragma unroll
      for (int j = 0; j < 8; ++j) av[j] = sgl[k+j];
#pragma unroll
      for (int j = 0; j < 8; ++j) a[j] = fmaf(av[j], wv[j], a[j]);
    }
    sBp[t] = fmaxf(((a[0]+a[1])+(a[2]+a[3])) + ((a[4]+a[5])+(a[6]+a[7])) + leb1[p*64 + t], 0.f);
  }
  __syncthreads();

  { // scb[128+t] = sA @ meW2_p + meb2 ; scb[192+t] = sB @ leW2_p + leb2
    const float* w  = meW2 + p*4096 + t;
    const float* w2 = leW2 + p*4096 + t;
    float a[8] = {0.f,0.f,0.f,0.f,0.f,0.f,0.f,0.f};
    float c[8] = {0.f,0.f,0.f,0.f,0.f,0.f,0.f,0.f};
    for (int k = 0; k < 64; k += 8) {
      float wv[8], vv[8], av[8], bv[8];
#pragma unroll
      for (int j = 0; j < 8; ++j) wv[j] = w[(k+j)*64];
#pragma unroll
      for (int j = 0; j < 8; ++j) vv[j] = w2[(k+j)*64];
#pragma unroll
      for (int j = 0; j < 8; ++j) { av[j] = sAp[k+j]; bv[j] = sBp[k+j]; }
#pragma unroll
      for (int j = 0; j < 8; ++j) {
        a[j] = fmaf(av[j], wv[j], a[j]);
        c[j] = fmaf(bv[j], vv[j], c[j]);
      }
    }
    scb[128 + t] = ((a[0]+a[1])+(a[2]+a[3])) + ((a[4]+a[5])+(a[6]+a[7])) + meb2[p*64 + t];
    scb[192 + t] = ((c[0]+c[1])+(c[2]+c[3])) + ((c[4]+c[5])+(c[6]+c[7])) + leb2[p*64 + t];
  }
  __syncthreads();

  { // sf1 = relu(scb @ fW1_p + fb1_p), K=256, cols t and t+64
    const float* w = fW1 + p*32768;
    float a[8] = {0.f,0.f,0.f,0.f,0.f,0.f,0.f,0.f};
    float c[8] = {0.f,0.f,0.f,0.f,0.f,0.f,0.f,0.f};
    for (int k = 0; k < 256; k += 8) {
      float w0[8], w1[8], av[8];
#pragma unroll
      for (int j = 0; j < 8; ++j) w0[j] = w[(k+j)*128 + t];
#pragma unroll
      for (int j = 0; j < 8; ++j) w1[j] = w[(k+j)*128 + 64 + t];
#pragma unroll
      for (int j = 0; j < 8; ++j) av[j] = scb[k+j];
#pragma unroll
      for (int j = 0; j < 8; ++j) {
        a[j] = fmaf(av[j], w0[j], a[j]);
        c[j] = fmaf(av[j], w1[j], c[j]);
      }
    }
    sf1[t]      = fmaxf(((a[0]+a[1])+(a[2]+a[3])) + ((a[4]+a[5])+(a[6]+a[7])) + fb1[p*128 + t], 0.f);
    sf1[64 + t] = fmaxf(((c[0]+c[1])+(c[2]+c[3])) + ((c[4]+c[5])+(c[6]+c[7])) + fb1[p*128 + 64 + t], 0.f);
  }
  __syncthreads();

  { // sf2 = sf1 @ fW2_p + fb2_p, K=128
    const float* w = fW2 + p*8192 + t;
    float a[8] = {0.f,0.f,0.f,0.f,0.f,0.f,0.f,0.f};
    for (int k = 0; k < 128; k += 8) {
      float wv[8], av[8];
#pragma unroll
      for (int j = 0; j < 8; ++j) wv[j] = w[(k+j)*64];
#pragma unroll
      for (int j = 0; j < 8; ++j) av[j] = sf1[k+j];
#pragma unroll
      for (int j = 0; j < 8; ++j) a[j] = fmaf(av[j], wv[j], a[j]);
    }
    sf2[t] = ((a[0]+a[1])+(a[2]+a[3])) + ((a[4]+a[5])+(a[6]+a[7])) + fb2[p*64 + t];
  }
  __syncthreads();

  { // h1 = relu(sf2 @ hW1_p + hb1_p)[32]; dot hW2_p; shfl-reduce
    float val = 0.f;
    if (t < 32) {
      const float* w = hW1 + p*2048 + t;
      float a[8] = {0.f,0.f,0.f,0.f,0.f,0.f,0.f,0.f};
      for (int k = 0; k < 64; k += 8) {
        float wv[8], av[8];
#pragma unroll
        for (int j = 0; j < 8; ++j) wv[j] = w[(k+j)*32];
#pragma unroll
        for (int j = 0; j < 8; ++j) av[j] = sf2[k+j];
#pragma unroll
        for (int j = 0; j < 8; ++j) a[j] = fmaf(av[j], wv[j], a[j]);
      }
      const float h1 = ((a[0]+a[1])+(a[2]+a[3])) + ((a[4]+a[5])+(a[6]+a[7])) + hb1[p*32 + t];
      val = fmaxf(h1, 0.f) * hW2[p*32 + t];
    }
#pragma unroll
    for (int o = 1; o < 32; o <<= 1) val += __shfl_xor(val, o);
    if (t == 0) out[p*1024 + b] = val + hb2[p];
  }
}

extern "C" void kernel_launch(void* const* d_in, const int* in_sizes, int n_in,
                              void* d_out, int out_size, void* d_ws, size_t ws_size,
                              hipStream_t stream) {
  const float* x_atoms    = (const float*)d_in[0];
  const float* pos        = (const float*)d_in[1];
  const float* molf       = (const float*)d_in[3];
  const float* emb_W      = (const float*)d_in[4];
  const float* emb_b      = (const float*)d_in[5];
  const float* mp_W1      = (const float*)d_in[6];
  const float* mp_b1      = (const float*)d_in[7];
  const float* mp_W2      = (const float*)d_in[8];
  const float* mp_b2      = (const float*)d_in[9];
  const float* ln_g       = (const float*)d_in[10];
  const float* ln_b       = (const float*)d_in[11];
  const float* attn_in_w  = (const float*)d_in[12];
  const float* attn_in_b  = (const float*)d_in[13];
  const float* attn_out_w = (const float*)d_in[14];
  const float* attn_out_b = (const float*)d_in[15];
  const float* pool_W     = (const float*)d_in[16];
  const float* pool_b     = (const float*)d_in[17];
  const float* mol_gate   = (const float*)d_in[18];
  const float* lrn_gate   = (const float*)d_in[19];
  const float* meW1       = (const float*)d_in[20];
  const float* meb1       = (const float*)d_in[21];
  const float* meW2       = (const float*)d_in[22];
  const float* meb2       = (const float*)d_in[23];
  const float* leW1       = (const float*)d_in[24];
  const float* leb1       = (const float*)d_in[25];
  const float* leW2       = (const float*)d_in[26];
  const float* leb2       = (const float*)d_in[27];
  const float* fW1        = (const float*)d_in[28];
  const float* fb1        = (const float*)d_in[29];
  const float* fW2        = (const float*)d_in[30];
  const float* fb2        = (const float*)d_in[31];
  const float* hW1        = (const float*)d_in[32];
  const float* hb1        = (const float*)d_in[33];
  const float* hW2        = (const float*)d_in[34];
  const float* hb2        = (const float*)d_in[35];
  const int*   ei         = (const int*)d_in[36];

  float* ws      = (float*)d_ws;
  float* x       = ws;                              // NN*128
  float* region  = x + (size_t)NN*128;              // NN*384 floats
  float* P       = region;                          // NN*128 fp32
  unsigned short* Qbf = (unsigned short*)(region + (size_t)NN*128); // NN*128 bf16
  float* dqkv    = region;                          // NN*384 (layer bufs dead)
  float* att     = region + (size_t)NN*384;         // NN*128
  float* csr_rf  = att + (size_t)NN*128;            // NE*4 floats (float4 records)
  float4* csr_rec = (float4*)csr_rf;
  int*   cnt_i   = (int*)(csr_rf + (size_t)NE*4);   // NN
  int*   csr_off = cnt_i + NN;                      // NN+64 (padded)
  int*   cur     = csr_off + NN + 64;               // NN
  float* pqbias  = (float*)(cur + NN);              // 768
  short* bh      = (short*)(pqbias + 768);          // PK_TOTAL shorts
  short* bl      = bh + PK_TOTAL;                   // PK_TOTAL shorts

  hipMemsetAsync(cnt_i, 0, (size_t)NN*sizeof(int), stream);

  prep_kernel<<<(PK_TOTAL + 255)/256, 256, 0, stream>>>(
      mp_W1, mp_W2, attn_in_w, attn_out_w, emb_W, mp_b1, bh, bl, pqbias);
  hist_kernel<<<NE/256, 256, 0, stream>>>(ei, cnt_i);
  scan_kernel<<<1, 1024, 0, stream>>>(cnt_i, csr_off, cur);
  scatter_kernel<<<NE/256, 256, 0, stream>>>(pos, ei, cur, csr_rec);

  // embed via MFMA: x = x_atoms @ emb_W + emb_b
  mfma_gemm_kernel<<<dim3(NN/128, 2), 256, 0, stream>>>(
      x_atoms, 64, 64, bh + EMB_OFF, bl + EMB_OFF, emb_b, x, 128, 128, 0, nullptr);

  for (int l = 0; l < 3; ++l) {
    mfma_gemm_kernel<<<dim3(NN/128, 4), 256, 0, stream>>>(
        x, 128, 128, bh + W1AB_OFF + l*32768, bl + W1AB_OFF + l*32768,
        pqbias + l*256, P, 256, 128, 0, Qbf);
    agg_kernel<<<NN/4, 256, 0, stream>>>(P, Qbf, csr_off, csr_rec,
                                         mp_W1 + (size_t)l*259*128);
    mfma_gemm_ln_kernel<<<NN/64, 256, 0, stream>>>(
        P, 128, bh + W2_OFF + l*16384, bl + W2_OFF + l*16384,
        mp_b2 + l*128, csr_off, ln_g + l*128, ln_b + l*128, x);
  }

  // attention path
  mfma_gemm_kernel<<<dim3(NN/128, 6), 256, 0, stream>>>(
      x, 128, 128, bh + WIN_OFF, bl + WIN_OFF, attn_in_b, dqkv, 384, 384, 0, nullptr);
  attn_kernel<<<NB, 128, 0, stream>>>(dqkv);
  mfma_gemm_kernel<<<dim3(NN/128, 2), 256, 0, stream>>>(
      dqkv + 256, 384, 128, bh + WOUT_OFF, bl + WOUT_OFF, attn_out_b, att, 128, 128, 0, nullptr);

  // fused pooling + proj + per-property head (wave = property)
  pool_head_kernel<<<NB, 256, 0, stream>>>(
      att, x, pool_W, pool_b, molf, mol_gate, lrn_gate,
      meW1, meb1, meW2, meb2, leW1, leb1, leW2, leb2,
      fW1, fb1, fW2, fb2, hW1, hb1, hW2, hb2, (float*)d_out);
}